// Round 10
// baseline (282.569 us; speedup 1.0000x reference)
//
#include <hip/hip_runtime.h>
#include <hip/hip_bf16.h>
#include <string.h>

typedef __hip_bfloat16 bf16;
typedef __attribute__((ext_vector_type(8))) short short8;
typedef __attribute__((ext_vector_type(4))) float f32x4;

#define Bsz 512
#define S3  512
#define Tsz 16
#define Cc  128
#define TT  15
#define XP  136   // X row stride in ushorts (272B = 16B-aligned rows)
#define EPSv 1e-5f

__device__ __forceinline__ float u2f(unsigned short u) {
    return __uint_as_float(((unsigned)u) << 16);
}
__device__ __forceinline__ float ulo(unsigned u) { return __uint_as_float(u << 16); }
__device__ __forceinline__ float uhi(unsigned u) { return __uint_as_float(u & 0xffff0000u); }
__device__ __forceinline__ unsigned short f2bu(float v) {
    bf16 h = __float2bfloat16(v);
    unsigned short u; memcpy(&u, &h, 2); return u;
}
// fast RNE bf16 (no NaN path — inputs finite)
__device__ __forceinline__ unsigned short bfr16(float a) {
    unsigned u = __float_as_uint(a);
    u = u + 0x7fffu + ((u >> 16) & 1u);
    return (unsigned short)(u >> 16);
}
// HW packed f32x2 -> bf16x2 (RNE), one VALU op. lo = a, hi = b.
__device__ __forceinline__ unsigned fpack2(float a, float b) {
    unsigned r;
    asm("v_cvt_pk_bf16_f32 %0, %1, %2" : "=v"(r) : "v"(a), "v"(b));
    return r;
}
__device__ __forceinline__ float dot4(float4 a, float4 b) {
    return a.x*b.x + a.y*b.y + a.z*b.z + a.w*b.w;
}

// ---------------------------------------------------------------------------
// X channel layout (k_torso): row-major 512 x 68 dwords; dword slot
// s = t2*16 + ml holds orig channels (32*t2 + ml) lo, (32*t2 + 16 + ml) hi —
// the two channels one MFMA C-lane owns, so LN packs via one cvt_pk.
// k_wpack interleaves the weight K-dim to match; N-dim is identity.
// ---------------------------------------------------------------------------

// ---------------------------------------------------------------------------
// k_tpack: src (NR x NK) row-major fp32 -> float4-packed k-major (Wl for base)
// ---------------------------------------------------------------------------
__global__ __launch_bounds__(256) void k_tpack(const float* __restrict__ src,
                                               float* __restrict__ dst,
                                               int NR, int NK)
{
    __shared__ float tile[32][33];
    int k0 = blockIdx.x * 32, r0 = blockIdx.y * 32;
    int lr = threadIdx.x >> 5, lk = threadIdx.x & 31;
    for (int i = lr; i < 32; i += 8)
        tile[i][lk] = src[(size_t)(r0 + i) * NK + k0 + lk];
    __syncthreads();
    int c = threadIdx.x & 31, k4 = threadIdx.x >> 5;
    float4 v;
    v.x = tile[c][k4 * 4 + 0]; v.y = tile[c][k4 * 4 + 1];
    v.z = tile[c][k4 * 4 + 2]; v.w = tile[c][k4 * 4 + 3];
    ((float4*)dst)[(size_t)(k0 / 4 + k4) * NR + r0 + c] = v;
}

// ---------------------------------------------------------------------------
// k_cvt5: all 5 transformer weights fp32 -> bf16 in one launch.
// ---------------------------------------------------------------------------
__global__ __launch_bounds__(256) void k_cvt5(
    const float* __restrict__ s0, const float* __restrict__ s1,
    const float* __restrict__ s2, const float* __restrict__ s3,
    const float* __restrict__ s4, ushort* __restrict__ dst)
{
    int i = blockIdx.x * 256 + threadIdx.x;
    if (i >= 114688) return;
    const float* src; int rel;
    if (i < 16384)      { src = s0; rel = i; }
    else if (i < 40960) { src = s1; rel = i - 16384; }
    else if (i < 49152) { src = s2; rel = i - 40960; }
    else if (i < 81920) { src = s3; rel = i - 49152; }
    else                { src = s4; rel = i - 81920; }
    float4 v = ((const float4*)src)[rel];
    ushort4 o;
    o.x = f2bu(v.x); o.y = f2bu(v.y); o.z = f2bu(v.z); o.w = f2bu(v.w);
    ((ushort4*)dst)[i] = o;
}

// ---------------------------------------------------------------------------
// k_wpack: Wl and Wr (3 x 128 x 128 fp32 each) -> bf16 MFMA-fragment-major,
// K-dim interleaved to match X's paired-channel layout:
// fragment elem j of (ks,q) <- orig col 32*ks + q*4 + (j>>1) + 16*(j&1).
// WB[((l*2 + which)*32 + (t*4+ks))*512 + lane*8 + j], which=0 Wl, 1 Wr.
// ---------------------------------------------------------------------------
__global__ __launch_bounds__(256) void k_wpack(
    const float* __restrict__ Wl, const float* __restrict__ Wr,
    ushort* __restrict__ WB)
{
    int l = blockIdx.x, w = blockIdx.y;
    const float* src = (w == 0 ? Wl : Wr) + l * 16384;
    ushort* dst = WB + (size_t)(l * 2 + w) * 32 * 512;
    for (int item = threadIdx.x; item < 2048; item += 256) {
        int f = item >> 6, lane = item & 63;
        int t = f >> 2, ks = f & 3, ml = lane & 15, q = lane >> 4;
        int n = t * 16 + ml;
        const float* sA = src + n * 128 + 32 * ks + q * 4;      // ch base
        const float* sB = sA + 16;                               // ch base + 16
        float4 a = *(const float4*)sA;
        float4 b = *(const float4*)sB;
        ushort4 o0, o1;
        o0.x = f2bu(a.x); o0.y = f2bu(b.x); o0.z = f2bu(a.y); o0.w = f2bu(b.y);
        o1.x = f2bu(a.z); o1.y = f2bu(b.z); o1.z = f2bu(a.w); o1.w = f2bu(b.w);
        ushort* dp = dst + (size_t)f * 512 + lane * 8;
        *(ushort4*)dp = o0;
        *(ushort4*)(dp + 4) = o1;
    }
}

// ---------------------------------------------------------------------------
// k_torso: fused init + 3 GNN layers + pool. 1024 threads (16 waves,
// 4 waves/SIMD). Wave wv owns rows [wv*32,wv*32+32); acc[8][2] = 64 AGPRs.
// Round-10: sp[8] (the masked column-sum for the next layer's base) is now
// declared/zeroed AFTER the GEMM barriers — in rounds 8-9 it was live across
// the whole MFMA region at the exactly-full 128-reg/wave budget, forcing
// ~8 dwords/layer of scratch spill (53-57 MB WRITE_SIZE). Epilogue reads
// sbase/gln/bln from LDS at use sites. D = Wr - inv*Wl built per layer into
// LDS one 16KB N-half at a time (straight-line macros, compile-time acc
// indices, rule #20); GEMM B via ds_read_b128. sred aliased into upper half
// of Ds; fC (frame0 staging) aliases its first 2KB. LDS 158788 <= 163840.
// ---------------------------------------------------------------------------
__global__ __launch_bounds__(1024) void k_torso(
    const int* __restrict__ xx, const float* __restrict__ ss,
    const float* __restrict__ Win, const float* __restrict__ b_in,
    const ushort* __restrict__ WB,
    const float4* __restrict__ WlP, const float* __restrict__ blv,
    const float* __restrict__ lng, const float* __restrict__ lnb,
    float* __restrict__ out)
{
    __shared__ ushort X[512 * XP];
    __shared__ ushort Ds[16 * 512];        // one N-half of D, fragment-major
    __shared__ ushort mCu[512];            // node mask as bf16 (1.0 / 0.0)
    __shared__ float  ssc[128];
    __shared__ float  sbase[128];
    __shared__ float  gln[128], bln[128];
    __shared__ float  scnt[8];
    __shared__ float  invS;

    int b = blockIdx.x, tid = threadIdx.x;
    int wv = tid >> 6, lane = tid & 63;      // wv in 0..15
    int ml = lane & 15, quad = lane >> 4;

    int*   fC   = (int*)Ds;                  // bytes [0, 2048): frame0 staging
    float* sred = (float*)(Ds + 4096);       // bytes [8192, 16384): 16x128 f32

    // ================= stage frame0 + mask + count =================
    const int* x0 = xx + (size_t)b * Tsz * S3;
    if (tid < 512) {
        int f0 = x0[tid];                    // coalesced, one per thread
        fC[tid] = f0;
        mCu[tid] = (f0 != 0) ? (ushort)0x3F80 : (ushort)0;
        unsigned long long bal = __ballot(f0 != 0);
        if (lane == 0) scnt[wv] = (float)__popcll(bal);
    }
    if (tid < 128) { gln[tid] = lng[tid]; bln[tid] = lnb[tid]; }
    __syncthreads();

    // ================= init features =================
    {
        int cp = lane;
        // slot cp holds orig channels (co0, co0+16)
        int co0 = 32 * (cp >> 4) + (cp & 15), co1 = co0 + 16;
        float f4c = ss[b] * (1.0f / 8.0f);
        float a0 = Win[co0*5+0], a1 = Win[co0*5+1], a2 = Win[co0*5+2], a3 = Win[co0*5+3];
        float c0 = Win[co1*5+0], c1 = Win[co1*5+1], c2 = Win[co1*5+2], c3 = Win[co1*5+3];
        float ba = b_in[co0] + f4c * Win[co0*5+4];
        float bc = b_in[co1] + f4c * Win[co1*5+4];
        float sp0 = 0.f, sp1 = 0.f;
        for (int node = wv; node < S3; node += 16) {
            int f0 = fC[node];               // LDS broadcast
            float m = (f0 != 0) ? 1.f : 0.f;
            float ci = (float)(node >> 6) * (1.f / 7.f);
            float cj = (float)((node >> 3) & 7) * (1.f / 7.f);
            float ck = (float)(node & 7) * (1.f / 7.f);
            float ft = (float)f0 * 0.5f;
            float v0 = ba + ci * a0 + cj * a1 + ck * a2 + ft * a3;
            float v1 = bc + ci * c0 + cj * c1 + ck * c2 + ft * c3;
            ((unsigned*)(X + node * XP))[cp] = fpack2(v0, v1);
            sp0 += v0 * m; sp1 += v1 * m;
        }
        sred[wv * 128 + co0] = sp0;          // disjoint from fC (bytes 8K+)
        sred[wv * 128 + co1] = sp1;
    }
    __syncthreads();
    if (tid == 0) {
        float n = 0.f;
#pragma unroll
        for (int g = 0; g < 8; g++) n += scnt[g];
        invS = (n > 1.f) ? 1.f / (n - 1.f) : 0.f;
    }
    __syncthreads();
    if (tid < 128) {
        float s = 0.f;
#pragma unroll
        for (int g = 0; g < 16; g++) s += sred[g * 128 + tid];
        ssc[tid] = s * invS;
    }
    __syncthreads();
    // sbase = blv + ssc @ WlP : 8-way K-split over all 1024 threads
    {
        int part = tid >> 7, c = tid & 127;
        float a = 0.f;
#pragma unroll
        for (int k4 = part * 4; k4 < part * 4 + 4; k4++)
            a += dot4(*(const float4*)(ssc + k4 * 4), WlP[k4 * 384 + c]);
        sred[part * 128 + c] = a;
    }
    __syncthreads();
    if (tid < 128) {
        float a = blv[tid];
#pragma unroll
        for (int p = 0; p < 8; p++) a += sred[p * 128 + tid];
        sbase[tid] = a;
    }
    __syncthreads();

    float ninv = -invS;   // wave-uniform; constant across layers

// D_BUILD(H): build N-half H of D = Wr - inv*Wl into Ds (bf16 fragments).
// 1024 threads, 1024 items of 8 ushorts -> one item per thread.
#define D_BUILD(H)                                                            \
    {                                                                         \
        const ushort* wl = WB + ((size_t)(l * 2 + 0) * 32 + (H) * 16) * 512;  \
        const ushort* wr = WB + ((size_t)(l * 2 + 1) * 32 + (H) * 16) * 512;  \
        int g = tid;                                                          \
        uint4 ul = *(const uint4*)(wl + g * 8);                               \
        uint4 ur = *(const uint4*)(wr + g * 8);                               \
        uint4 d;                                                              \
        d.x = fpack2(fmaf(ninv, ulo(ul.x), ulo(ur.x)), fmaf(ninv, uhi(ul.x), uhi(ur.x))); \
        d.y = fpack2(fmaf(ninv, ulo(ul.y), ulo(ur.y)), fmaf(ninv, uhi(ul.y), uhi(ur.y))); \
        d.z = fpack2(fmaf(ninv, ulo(ul.z), ulo(ur.z)), fmaf(ninv, uhi(ul.z), uhi(ur.z))); \
        d.w = fpack2(fmaf(ninv, ulo(ul.w), ulo(ur.w)), fmaf(ninv, uhi(ul.w), uhi(ur.w))); \
        *(uint4*)(Ds + g * 8) = d;                                            \
    }

// GEMM_HALF(OFF): acc[OFF..OFF+3] += x-tile @ Ds^T. OFF literal -> all acc
// indices compile-time (rule #20). Round-0-proven register footprint.
#define GEMM_HALF(OFF)                                                        \
    _Pragma("unroll")                                                         \
    for (int ks = 0; ks < 4; ks++) {                                          \
        short8 a0 = *(const short8*)(xr0 + ks * 32);                          \
        short8 a1 = *(const short8*)(xr1 + ks * 32);                          \
        short8 bg[4];                                                         \
        _Pragma("unroll")                                                     \
        for (int t = 0; t < 4; t++)                                           \
            bg[t] = *(const short8*)(Ds + (size_t)(t * 4 + ks) * 512 + lane * 8); \
        _Pragma("unroll")                                                     \
        for (int t = 0; t < 4; t++) {                                         \
            acc[(OFF) + t][0] = __builtin_amdgcn_mfma_f32_16x16x32_bf16(a0, bg[t], acc[(OFF) + t][0], 0, 0, 0); \
            acc[(OFF) + t][1] = __builtin_amdgcn_mfma_f32_16x16x32_bf16(a1, bg[t], acc[(OFF) + t][1], 0, 0, 0); \
        }                                                                     \
    }

    // ================= 3 SAGE layers =================
    for (int l = 0; l < 3; l++) {
        bool last = (l == 2);

        f32x4 acc[8][2];   // [n-tile][m-subtile]: 32 rows x 128 cols per wave
#pragma unroll
        for (int t = 0; t < 8; t++)
#pragma unroll
            for (int mm = 0; mm < 2; mm++) acc[t][mm] = (f32x4){0.f, 0.f, 0.f, 0.f};

        const ushort* xr0 = X + (wv * 32 + ml) * XP + quad * 8;
        const ushort* xr1 = xr0 + 16 * XP;

        // two N-halves, straight-line (compile-time acc indices):
        D_BUILD(0); __syncthreads(); GEMM_HALF(0); __syncthreads();
        D_BUILD(1); __syncthreads(); GEMM_HALF(4); __syncthreads();

        // sp declared HERE (not before the GEMM): it must not be live across
        // the MFMA region — rounds 8-9 had it live there and spilled ~8
        // dwords/layer at the exactly-full register budget.
        float sp[8];
#pragma unroll
        for (int t = 0; t < 8; t++) sp[t] = 0.f;

        // epilogue: relu+base -> LN (shuffle stats) -> paired bf16 into X.
#pragma unroll
        for (int mm = 0; mm < 2; mm++) {
#pragma unroll
            for (int r = 0; r < 4; r++) {
                int row = wv * 32 + mm * 16 + quad * 4 + r;
                float s = 0.f, q = 0.f;
#pragma unroll
                for (int t = 0; t < 8; t++) {
                    float vv = fmaxf(acc[t][mm][r] + sbase[t * 16 + ml], 0.f);
                    acc[t][mm][r] = vv;
                    s += vv; q = fmaf(vv, vv, q);
                }
#pragma unroll
                for (int off = 1; off <= 8; off <<= 1) {
                    s += __shfl_xor(s, off, 64);
                    q += __shfl_xor(q, off, 64);
                }
                float mu = s * (1.f / 128.f);
                float rs = rsqrtf(q * (1.f / 128.f) - mu * mu + EPSv);
                float mrow = u2f(mCu[row]);
                unsigned* xr32 = (unsigned*)(X + row * XP);
                if (last) {
#pragma unroll
                    for (int t2 = 0; t2 < 4; t2++) {
                        float y0 = ((acc[2*t2][mm][r]   - mu) * rs * gln[(2*t2)*16 + ml]   + bln[(2*t2)*16 + ml])   * mrow;
                        float y1 = ((acc[2*t2+1][mm][r] - mu) * rs * gln[(2*t2+1)*16 + ml] + bln[(2*t2+1)*16 + ml]) * mrow;
                        xr32[t2 * 16 + ml] = fpack2(y0, y1);
                    }
                } else {
#pragma unroll
                    for (int t2 = 0; t2 < 4; t2++) {
                        float y0 = (acc[2*t2][mm][r]   - mu) * rs * gln[(2*t2)*16 + ml]   + bln[(2*t2)*16 + ml];
                        float y1 = (acc[2*t2+1][mm][r] - mu) * rs * gln[(2*t2+1)*16 + ml] + bln[(2*t2+1)*16 + ml];
                        sp[2*t2]   = fmaf(y0, mrow, sp[2*t2]);
                        sp[2*t2+1] = fmaf(y1, mrow, sp[2*t2+1]);
                        xr32[t2 * 16 + ml] = fpack2(y0, y1);
                    }
                }
            }
        }

        if (!last) {
#pragma unroll
            for (int t = 0; t < 8; t++) {
                sp[t] += __shfl_xor(sp[t], 16, 64);
                sp[t] += __shfl_xor(sp[t], 32, 64);
            }
            if (quad == 0) {
#pragma unroll
                for (int t = 0; t < 8; t++) sred[wv * 128 + t * 16 + ml] = sp[t];
            }
            __syncthreads();
            if (tid < 128) {
                float s = 0.f;
#pragma unroll
                for (int g = 0; g < 16; g++) s += sred[g * 128 + tid];
                ssc[tid] = s * invS;
            }
            __syncthreads();
            {
                int part = tid >> 7, c = tid & 127;
                float a = 0.f;
#pragma unroll
                for (int k4 = part * 4; k4 < part * 4 + 4; k4++)
                    a += dot4(*(const float4*)(ssc + k4 * 4), WlP[k4 * 384 + (l + 1) * 128 + c]);
                sred[part * 128 + c] = a;
            }
            __syncthreads();
            if (tid < 128) {
                float a = blv[(l + 1) * 128 + tid];
#pragma unroll
                for (int p = 0; p < 8; p++) a += sred[p * 128 + tid];
                sbase[tid] = a;
            }
            __syncthreads();
        }
    }
    __syncthreads();

    // ================= pool: slice means (paired-channel layout) ==========
    if (tid < 768) {
        int c4 = tid & 31, p = tid >> 5;
        int axis = p >> 3, idx = p & 7;
        float4 sum = {0.f, 0.f, 0.f, 0.f};
        for (int t = 0; t < 64; t++) {
            int node;
            if (axis == 0)      node = idx * 64 + t;
            else if (axis == 1) node = (t >> 3) * 64 + idx * 8 + (t & 7);
            else                node = t * 8 + idx;
            uint2 pk = *(const uint2*)(X + node * XP + c4 * 4);
            sum.x += ulo(pk.x);   // ch E0
            sum.y += uhi(pk.x);   // ch E0+16
            sum.z += ulo(pk.y);   // ch E0+1
            sum.w += uhi(pk.y);   // ch E0+17
        }
        int E0 = 32 * (c4 >> 3) + 2 * (c4 & 7);
        float* ob = out + (size_t)b * 26 * Cc + p * Cc;
        float2 lo = {sum.x * (1.f / 64.f), sum.z * (1.f / 64.f)};
        float2 hi = {sum.y * (1.f / 64.f), sum.w * (1.f / 64.f)};
        *(float2*)(ob + E0)      = lo;
        *(float2*)(ob + E0 + 16) = hi;
    }
}

// ---------------------------------------------------------------------------
// k_tf3: transformer, bf16 MFMA GEMMs; q/k/v stored bf16 (~50 KB LDS).
// Round-10: __launch_bounds__(512, 4) GUARANTEES <=128 regs/wave -> 2
// blocks/CU co-residency (without it the compiler may exceed 128 and halve
// occupancy silently). LN stats+apply fused into ONE phase per LN (wave-per-
// row shuffle stats, no mu_s/rs_s LDS round-trip) — removes 4 barriers.
// Attention on 480 threads (8 lanes per (h,tq) pair, 3x shfl_xor reduce).
// ---------------------------------------------------------------------------
__global__ __launch_bounds__(512, 4) void k_tf3(
    const int* __restrict__ xx, const float* __restrict__ ss,
    const ushort* __restrict__ WactB, const float* __restrict__ bact,
    const ushort* __restrict__ WqkvB, const float* __restrict__ bqkv,
    const ushort* __restrict__ WoB, const float* __restrict__ bo,
    const float* __restrict__ ln1g, const float* __restrict__ ln1b,
    const float* __restrict__ ln2g, const float* __restrict__ ln2b,
    const ushort* __restrict__ W1B, const float* __restrict__ b1v,
    const ushort* __restrict__ W2B, const float* __restrict__ b2v,
    const float* __restrict__ Wsc, const float* __restrict__ bsc,
    float* __restrict__ out)
{
    __shared__ float  As[TT * 132];
    __shared__ ushort Qs[16 * 392];
    __shared__ ushort Ab[16 * 136];
    __shared__ ushort Hs[16 * 136];
    __shared__ ushort Fs[16 * 520];
    __shared__ float  Att[60 * 16];

    int b = blockIdx.x, tid = threadIdx.x;
    int wv = tid >> 6, lane = tid & 63;      // wv in 0..7
    int ml = lane & 15, quad = lane >> 4;

    const int* xa = xx + (size_t)b * Tsz * S3 + S3;
    {
        const int4* xa4 = (const int4*)xa;          // 15*512/4 = 1920
        for (int i = tid; i < 1920; i += 512) {
            int4 v = xa4[i];
            int t = i >> 7, s = (i & 127) << 2;     // 128 int4 per row
            ushort4 o;
            o.x = bfr16((float)v.x); o.y = bfr16((float)v.y);
            o.z = bfr16((float)v.z); o.w = bfr16((float)v.w);
            *(ushort4*)(Fs + t * 520 + s) = o;
        }
    }
    __syncthreads();

    // act embedding: N=128 -> 8 tiles, wave wv owns tile wv (K=512)
    {
        f32x4 acc = (f32x4){0.f, 0.f, 0.f, 0.f};
        const ushort* ar = Fs + ml * 520 + quad * 8;
        const ushort* wb = WactB + (size_t)(wv * 16 + ml) * 512 + quad * 8;
        for (int ks = 0; ks < 16; ks++) {
            short8 a   = *(const short8*)(ar + ks * 32);
            short8 bfr = *(const short8*)(wb + ks * 32);
            acc = __builtin_amdgcn_mfma_f32_16x16x32_bf16(a, bfr, acc, 0, 0, 0);
        }
        int col = wv * 16 + ml;
        float bb = bact[col];
#pragma unroll
        for (int r = 0; r < 4; r++) {
            int row = quad * 4 + r;
            if (row < TT) As[row * 132 + col] = acc[r] + bb;
        }
    }
    __syncthreads();

    for (int l = 0; l < 2; l++) {
        const float* bq  = bqkv + l * 384;
        const float* bol = bo + l * 128;
        const float* g1  = ln1g + l * 128; const float* be1 = ln1b + l * 128;
        const float* g2  = ln2g + l * 128; const float* be2 = ln2b + l * 128;
        const float* b1l = b1v + l * 512;  const float* b2l = b2v + l * 128;

        // LN1 fused (stats + apply + pack in one phase; wave r does rows
        // r, r+8; each lane owns 2 channels)
        for (int r = wv; r < TT; r += 8) {
            float2 v = *(const float2*)(As + r * 132 + lane * 2);
            float s = v.x + v.y, q = v.x * v.x + v.y * v.y;
            for (int off = 32; off; off >>= 1) {
                s += __shfl_xor(s, off, 64);
                q += __shfl_xor(q, off, 64);
            }
            float mu = s * (1.f / 128.f);
            float rs = rsqrtf(q * (1.f / 128.f) - mu * mu + EPSv);
            float x0 = (v.x - mu) * rs * g1[2 * lane]     + be1[2 * lane];
            float x1 = (v.y - mu) * rs * g1[2 * lane + 1] + be1[2 * lane + 1];
            ((unsigned*)(Ab + r * 136))[lane] = fpack2(x0, x1);
        }
        __syncthreads();

        // qkv (K=128, N=384 -> 24 tiles, 3 per wave) -> Qs bf16
        {
            short8 a[4];
            const ushort* ar = Ab + ml * 136 + quad * 8;
#pragma unroll
            for (int ks = 0; ks < 4; ks++) a[ks] = *(const short8*)(ar + ks * 32);
#pragma unroll
            for (int i = 0; i < 3; i++) {
                int n0 = (wv * 3 + i) * 16;
                f32x4 acc = (f32x4){0.f, 0.f, 0.f, 0.f};
                const ushort* wb = WqkvB + (size_t)(l * 384 + n0 + ml) * 128 + quad * 8;
#pragma unroll
                for (int ks = 0; ks < 4; ks++) {
                    short8 bfr = *(const short8*)(wb + ks * 32);
                    acc = __builtin_amdgcn_mfma_f32_16x16x32_bf16(a[ks], bfr, acc, 0, 0, 0);
                }
                int col = n0 + ml;
                float bb = bq[col];
#pragma unroll
                for (int r = 0; r < 4; r++) {
                    int row = quad * 4 + r;
                    if (row < TT) Qs[row * 392 + col] = bfr16(acc[r] + bb);
                }
            }
        }
        __syncthreads();

        // attention scores + softmax: 480 threads, 8 lanes per (h,tq) pair,
        // each lane 4 channels; 3x shfl_xor sums the eighths.
        if (tid < 480) {
            int pair = tid >> 3, part = tid & 7;
            int h = pair / 15, tq = pair % 15;
            const ushort* qp = Qs + tq * 392 + h * 32 + part * 4;
            float sc[TT];
#pragma unroll
            for (int tk = 0; tk < TT; tk++) {
                const ushort* kp = Qs + tk * 392 + 128 + h * 32 + part * 4;
                uint2 qa = *(const uint2*)(qp);
                uint2 ka = *(const uint2*)(kp);
                float d = ulo(qa.x) * ulo(ka.x) + uhi(qa.x) * uhi(ka.x)
                        + ulo(qa.y) * ulo(ka.y) + uhi(qa.y) * uhi(ka.y);
                d += __shfl_xor(d, 1, 64);
                d += __shfl_xor(d, 2, 64);
                d += __shfl_xor(d, 4, 64);
                sc[tk] = d * 0.17677669529663689f;
            }
            if (part == 0) {
                float mx = -1e30f;
#pragma unroll
                for (int tk = 0; tk < TT; tk++) mx = fmaxf(mx, sc[tk]);
                float sum = 0.f;
#pragma unroll
                for (int tk = 0; tk < TT; tk++) { float e = __expf(sc[tk] - mx); sc[tk] = e; sum += e; }
                float r = 1.f / sum;
#pragma unroll
                for (int tk = 0; tk < TT; tk++) Att[pair * 16 + tk] = sc[tk] * r;
            }
        }
        __syncthreads();

        // o = att @ v -> Hs (bf16)
        for (int f = tid; f < TT * 64; f += 512) {
            int t = f >> 6, cp = f & 63;
            int h = cp >> 4;
            const float* ap = Att + (h * 15 + t) * 16;
            const ushort* vp = Qs + 256 + 2 * cp;
            float a0 = 0.f, a1 = 0.f;
#pragma unroll
            for (int tk = 0; tk < TT; tk++) {
                float w = ap[tk];
                unsigned pk = *(const unsigned*)(vp + tk * 392);
                a0 += w * ulo(pk);
                a1 += w * uhi(pk);
            }
            ((unsigned*)(Hs + t * 136))[cp] = fpack2(a0, a1);
        }
        __syncthreads();

        // proj + residual: N=128 -> 8 tiles, 1 per wave
        {
            short8 a[4];
            const ushort* ar = Hs + ml * 136 + quad * 8;
#pragma unroll
            for (int ks = 0; ks < 4; ks++) a[ks] = *(const short8*)(ar + ks * 32);
            int n0 = wv * 16;
            f32x4 acc = (f32x4){0.f, 0.f, 0.f, 0.f};
            const ushort* wb = WoB + (size_t)(l * 128 + n0 + ml) * 128 + quad * 8;
#pragma unroll
            for (int ks = 0; ks < 4; ks++) {
                short8 bfr = *(const short8*)(wb + ks * 32);
                acc = __builtin_amdgcn_mfma_f32_16x16x32_bf16(a[ks], bfr, acc, 0, 0, 0);
            }
            int col = n0 + ml;
            float bb = bol[col];
#pragma unroll
            for (int r = 0; r < 4; r++) {
                int row = quad * 4 + r;
                if (row < TT) As[row * 132 + col] += acc[r] + bb;
            }
        }
        __syncthreads();

        // LN2 fused
        for (int r = wv; r < TT; r += 8) {
            float2 v = *(const float2*)(As + r * 132 + lane * 2);
            float s = v.x + v.y, q = v.x * v.x + v.y * v.y;
            for (int off = 32; off; off >>= 1) {
                s += __shfl_xor(s, off, 64);
                q += __shfl_xor(q, off, 64);
            }
            float mu = s * (1.f / 128.f);
            float rs = rsqrtf(q * (1.f / 128.f) - mu * mu + EPSv);
            float x0 = (v.x - mu) * rs * g2[2 * lane]     + be2[2 * lane];
            float x1 = (v.y - mu) * rs * g2[2 * lane + 1] + be2[2 * lane + 1];
            ((unsigned*)(Ab + r * 136))[lane] = fpack2(x0, x1);
        }
        __syncthreads();

        // ff1 (K=128, N=512 -> 32 tiles, 4 per wave)
        {
            short8 a[4];
            const ushort* ar = Ab + ml * 136 + quad * 8;
#pragma unroll
            for (int ks = 0; ks < 4; ks++) a[ks] = *(const short8*)(ar + ks * 32);
#pragma unroll
            for (int i = 0; i < 4; i++) {
                int n0 = (wv * 4 + i) * 16;
                f32x4 acc = (f32x4){0.f, 0.f, 0.f, 0.f};
                const ushort* wb = W1B + (size_t)(l * 512 + n0 + ml) * 128 + quad * 8;
#pragma unroll
                for (int ks = 0; ks < 4; ks++) {
                    short8 bfr = *(const short8*)(wb + ks * 32);
                    acc = __builtin_amdgcn_mfma_f32_16x16x32_bf16(a[ks], bfr, acc, 0, 0, 0);
                }
                int col = n0 + ml;
                float bb = b1l[col];
#pragma unroll
                for (int r = 0; r < 4; r++) {
                    int row = quad * 4 + r;
                    if (row < TT) Fs[row * 520 + col] = bfr16(fmaxf(acc[r] + bb, 0.f));
                }
            }
        }
        __syncthreads();

        // ff2 + residual (K=512, N=128 -> 8 tiles, 1 per wave)
        {
            f32x4 acc = (f32x4){0.f, 0.f, 0.f, 0.f};
            const ushort* ar = Fs + ml * 520 + quad * 8;
            int n0 = wv * 16;
            const ushort* wb = W2B + (size_t)(l * 128 + n0 + ml) * 512 + quad * 8;
            for (int ks = 0; ks < 16; ks++) {
                short8 a   = *(const short8*)(ar + ks * 32);
                short8 bfr = *(const short8*)(wb + ks * 32);
                acc = __builtin_amdgcn_mfma_f32_16x16x32_bf16(a, bfr, acc, 0, 0, 0);
            }
            int col = n0 + ml;
            float bb = b2l[col];
#pragma unroll
            for (int r = 0; r < 4; r++) {
                int row = quad * 4 + r;
                if (row < TT) As[row * 132 + col] += acc[r] + bb;
            }
        }
        __syncthreads();
    }

    if (tid < 128) {
        float s = 0.f;
#pragma unroll
        for (int t = 0; t < TT; t++) s += As[t * 132 + tid];
        out[(size_t)b * 26 * Cc + 24 * Cc + tid] = s * (1.f / 15.f);
    } else if (tid < 256) {
        int co = tid - 128;
        float v = ss[b] * Wsc[co] + bsc[co];
        out[(size_t)b * 26 * Cc + 25 * Cc + co] = fmaxf(v, 0.f);
    }
}

// ---------------------------------------------------------------------------
extern "C" void kernel_launch(void* const* d_in, const int* in_sizes, int n_in,
                              void* d_out, int out_size, void* d_ws, size_t ws_size,
                              hipStream_t stream)
{
    (void)in_sizes; (void)n_in; (void)out_size; (void)ws_size;
    const int*   xx   = (const int*)d_in[0];
    const float* ss   = (const float*)d_in[1];
    const float* Win  = (const float*)d_in[2];
    const float* b_in = (const float*)d_in[3];
    const float* Wl   = (const float*)d_in[4];
    const float* bl   = (const float*)d_in[5];
    const float* Wr   = (const float*)d_in[6];
    const float* lng  = (const float*)d_in[7];
    const float* lnb  = (const float*)d_in[8];
    const float* Wqkv = (const float*)d_in[9];
    const float* bqkv = (const float*)d_in[10];
    const float* Wo   = (const float*)d_in[11];
    const float* bo   = (const float*)d_in[12];
    const float* ln1g = (const float*)d_in[13];
    const float* ln1b = (const float*)d_in[14];
    const float* ln2g = (const float*)d_in[15];
    const float* ln2b = (const float*)d_in[16];
    const float* W1   = (const float*)d_in[17];
    const float* b1   = (const float*)d_in[18];
    const float* W2   = (const float*)d_in[19];
    const float* b2   = (const float*)d_in[20];
    const float* Wact = (const float*)d_in[21];
    const float* bact = (const float*)d_in[22];
    const float* Wsc  = (const float*)d_in[23];
    const float* bsc  = (const float*)d_in[24];
    float* out = (float*)d_out;

    char* ws = (char*)d_ws;
    size_t off = 0;
    float* WlT  = (float*)(ws + off); off += 384 * 128 * 4;
    ushort* WB    = (ushort*)(ws + off); off += (size_t)3 * 2 * 128 * 128 * 2;
    ushort* WactB = (ushort*)(ws + off); off += 128 * 512 * 2;
    ushort* WqkvB = (ushort*)(ws + off); off += 768 * 128 * 2;
    ushort* WoB   = (ushort*)(ws + off); off += 256 * 128 * 2;
    ushort* W1B   = (ushort*)(ws + off); off += 1024 * 128 * 2;
    ushort* W2B   = (ushort*)(ws + off); off += 256 * 512 * 2;

    k_tpack<<<dim3(4, 12), 256, 0, stream>>>(Wl, WlT, 384, 128);
    k_cvt5<<<448, 256, 0, stream>>>(Wact, Wqkv, Wo, W1, W2, WactB);
    k_wpack<<<dim3(3, 2), 256, 0, stream>>>(Wl, Wr, WB);

    k_torso<<<Bsz, 1024, 0, stream>>>(xx, ss, Win, b_in, WB,
                                      (const float4*)WlT, bl, lng, lnb, out);

    k_tf3<<<Bsz, 512, 0, stream>>>(xx, ss,
                                   WactB, bact, WqkvB, bqkv, WoB, bo,
                                   ln1g, ln1b, ln2g, ln2b,
                                   W1B, b1, W2B, b2,
                                   Wsc, bsc, out);
}

// Round 11
// 281.692 us; speedup vs baseline: 1.0031x; 1.0031x over previous
//
#include <hip/hip_runtime.h>
#include <hip/hip_bf16.h>
#include <string.h>

typedef __hip_bfloat16 bf16;
typedef __attribute__((ext_vector_type(8))) short short8;
typedef __attribute__((ext_vector_type(4))) float f32x4;

#define Bsz 512
#define S3  512
#define Tsz 16
#define Cc  128
#define TT  15
#define XP  136   // X row stride in ushorts (272B = 16B-aligned rows)
#define EPSv 1e-5f

__device__ __forceinline__ float u2f(unsigned short u) {
    return __uint_as_float(((unsigned)u) << 16);
}
__device__ __forceinline__ float ulo(unsigned u) { return __uint_as_float(u << 16); }
__device__ __forceinline__ float uhi(unsigned u) { return __uint_as_float(u & 0xffff0000u); }
__device__ __forceinline__ unsigned short f2bu(float v) {
    bf16 h = __float2bfloat16(v);
    unsigned short u; memcpy(&u, &h, 2); return u;
}
// fast RNE bf16 (no NaN path — inputs finite)
__device__ __forceinline__ unsigned short bfr16(float a) {
    unsigned u = __float_as_uint(a);
    u = u + 0x7fffu + ((u >> 16) & 1u);
    return (unsigned short)(u >> 16);
}
// HW packed f32x2 -> bf16x2 (RNE), one VALU op. lo = a, hi = b.
__device__ __forceinline__ unsigned fpack2(float a, float b) {
    unsigned r;
    asm("v_cvt_pk_bf16_f32 %0, %1, %2" : "=v"(r) : "v"(a), "v"(b));
    return r;
}
__device__ __forceinline__ float dot4(float4 a, float4 b) {
    return a.x*b.x + a.y*b.y + a.z*b.z + a.w*b.w;
}

// ---------------------------------------------------------------------------
// X channel layout (k_torso): row-major 512 x 68 dwords; dword slot
// s = t2*16 + ml holds orig channels (32*t2 + ml) lo, (32*t2 + 16 + ml) hi —
// the two channels one MFMA C-lane owns, so LN packs via one cvt_pk.
// k_wpack interleaves the weight K-dim to match; N-dim is identity.
// ---------------------------------------------------------------------------

// ---------------------------------------------------------------------------
// k_tpack: src (NR x NK) row-major fp32 -> float4-packed k-major (Wl for base)
// ---------------------------------------------------------------------------
__global__ __launch_bounds__(256) void k_tpack(const float* __restrict__ src,
                                               float* __restrict__ dst,
                                               int NR, int NK)
{
    __shared__ float tile[32][33];
    int k0 = blockIdx.x * 32, r0 = blockIdx.y * 32;
    int lr = threadIdx.x >> 5, lk = threadIdx.x & 31;
    for (int i = lr; i < 32; i += 8)
        tile[i][lk] = src[(size_t)(r0 + i) * NK + k0 + lk];
    __syncthreads();
    int c = threadIdx.x & 31, k4 = threadIdx.x >> 5;
    float4 v;
    v.x = tile[c][k4 * 4 + 0]; v.y = tile[c][k4 * 4 + 1];
    v.z = tile[c][k4 * 4 + 2]; v.w = tile[c][k4 * 4 + 3];
    ((float4*)dst)[(size_t)(k0 / 4 + k4) * NR + r0 + c] = v;
}

// ---------------------------------------------------------------------------
// k_cvt5: all 5 transformer weights fp32 -> bf16 in one launch.
// ---------------------------------------------------------------------------
__global__ __launch_bounds__(256) void k_cvt5(
    const float* __restrict__ s0, const float* __restrict__ s1,
    const float* __restrict__ s2, const float* __restrict__ s3,
    const float* __restrict__ s4, ushort* __restrict__ dst)
{
    int i = blockIdx.x * 256 + threadIdx.x;
    if (i >= 114688) return;
    const float* src; int rel;
    if (i < 16384)      { src = s0; rel = i; }
    else if (i < 40960) { src = s1; rel = i - 16384; }
    else if (i < 49152) { src = s2; rel = i - 40960; }
    else if (i < 81920) { src = s3; rel = i - 49152; }
    else                { src = s4; rel = i - 81920; }
    float4 v = ((const float4*)src)[rel];
    ushort4 o;
    o.x = f2bu(v.x); o.y = f2bu(v.y); o.z = f2bu(v.z); o.w = f2bu(v.w);
    ((ushort4*)dst)[i] = o;
}

// ---------------------------------------------------------------------------
// k_wpack: Wl and Wr (3 x 128 x 128 fp32 each) -> bf16 MFMA-fragment-major,
// K-dim interleaved to match X's paired-channel layout:
// fragment elem j of (ks,q) <- orig col 32*ks + q*4 + (j>>1) + 16*(j&1).
// WB[((l*2 + which)*32 + (t*4+ks))*512 + lane*8 + j], which=0 Wl, 1 Wr.
// ---------------------------------------------------------------------------
__global__ __launch_bounds__(256) void k_wpack(
    const float* __restrict__ Wl, const float* __restrict__ Wr,
    ushort* __restrict__ WB)
{
    int l = blockIdx.x, w = blockIdx.y;
    const float* src = (w == 0 ? Wl : Wr) + l * 16384;
    ushort* dst = WB + (size_t)(l * 2 + w) * 32 * 512;
    for (int item = threadIdx.x; item < 2048; item += 256) {
        int f = item >> 6, lane = item & 63;
        int t = f >> 2, ks = f & 3, ml = lane & 15, q = lane >> 4;
        int n = t * 16 + ml;
        const float* sA = src + n * 128 + 32 * ks + q * 4;      // ch base
        const float* sB = sA + 16;                               // ch base + 16
        float4 a = *(const float4*)sA;
        float4 b = *(const float4*)sB;
        ushort4 o0, o1;
        o0.x = f2bu(a.x); o0.y = f2bu(b.x); o0.z = f2bu(a.y); o0.w = f2bu(b.y);
        o1.x = f2bu(a.z); o1.y = f2bu(b.z); o1.z = f2bu(a.w); o1.w = f2bu(b.w);
        ushort* dp = dst + (size_t)f * 512 + lane * 8;
        *(ushort4*)dp = o0;
        *(ushort4*)(dp + 4) = o1;
    }
}

// ---------------------------------------------------------------------------
// k_torso: fused init + 3 GNN layers + pool. 1024 threads (16 waves,
// 4 waves/SIMD).
// Round-11: ROW-PHASED layers. Rounds 8-10 proved the 64-AGPR acc[8][2]
// structurally spills (~50 MB) at the 128-reg/wave 16-wave budget (arch cap
// 64), regardless of source-level live-range tweaks. Now wave wv owns 16
// rows per phase; each layer runs two sequential row-phases (rp=0: rows
// 0-255, rp=1: rows 256-511) with acc[8] = 32 AGPRs -> 96 arch regs -> no
// spill. X-update hazard is avoided because phase-0's epilogue writes rows
// 0-255 while phase-1's GEMM reads rows 256-511 (disjoint); Ds is rebuilt
// per phase (cheap). rp is runtime but touches ADDRESSES only — every acc
// index stays compile-time (rule #20). D = Wr - inv*Wl built into LDS one
// 16KB N-half at a time; GEMM B via ds_read_b128. sred aliased into upper
// half of Ds; fC (frame0 staging) aliases its first 2KB. LDS 158788.
// ---------------------------------------------------------------------------
__global__ __launch_bounds__(1024) void k_torso(
    const int* __restrict__ xx, const float* __restrict__ ss,
    const float* __restrict__ Win, const float* __restrict__ b_in,
    const ushort* __restrict__ WB,
    const float4* __restrict__ WlP, const float* __restrict__ blv,
    const float* __restrict__ lng, const float* __restrict__ lnb,
    float* __restrict__ out)
{
    __shared__ ushort X[512 * XP];
    __shared__ ushort Ds[16 * 512];        // one N-half of D, fragment-major
    __shared__ ushort mCu[512];            // node mask as bf16 (1.0 / 0.0)
    __shared__ float  ssc[128];
    __shared__ float  sbase[128];
    __shared__ float  gln[128], bln[128];
    __shared__ float  scnt[8];
    __shared__ float  invS;

    int b = blockIdx.x, tid = threadIdx.x;
    int wv = tid >> 6, lane = tid & 63;      // wv in 0..15
    int ml = lane & 15, quad = lane >> 4;

    int*   fC   = (int*)Ds;                  // bytes [0, 2048): frame0 staging
    float* sred = (float*)(Ds + 4096);       // bytes [8192, 16384): 16x128 f32

    // ================= stage frame0 + mask + count =================
    const int* x0 = xx + (size_t)b * Tsz * S3;
    if (tid < 512) {
        int f0 = x0[tid];                    // coalesced, one per thread
        fC[tid] = f0;
        mCu[tid] = (f0 != 0) ? (ushort)0x3F80 : (ushort)0;
        unsigned long long bal = __ballot(f0 != 0);
        if (lane == 0) scnt[wv] = (float)__popcll(bal);
    }
    if (tid < 128) { gln[tid] = lng[tid]; bln[tid] = lnb[tid]; }
    __syncthreads();

    // ================= init features =================
    {
        int cp = lane;
        // slot cp holds orig channels (co0, co0+16)
        int co0 = 32 * (cp >> 4) + (cp & 15), co1 = co0 + 16;
        float f4c = ss[b] * (1.0f / 8.0f);
        float a0 = Win[co0*5+0], a1 = Win[co0*5+1], a2 = Win[co0*5+2], a3 = Win[co0*5+3];
        float c0 = Win[co1*5+0], c1 = Win[co1*5+1], c2 = Win[co1*5+2], c3 = Win[co1*5+3];
        float ba = b_in[co0] + f4c * Win[co0*5+4];
        float bc = b_in[co1] + f4c * Win[co1*5+4];
        float sp0 = 0.f, sp1 = 0.f;
        for (int node = wv; node < S3; node += 16) {
            int f0 = fC[node];               // LDS broadcast
            float m = (f0 != 0) ? 1.f : 0.f;
            float ci = (float)(node >> 6) * (1.f / 7.f);
            float cj = (float)((node >> 3) & 7) * (1.f / 7.f);
            float ck = (float)(node & 7) * (1.f / 7.f);
            float ft = (float)f0 * 0.5f;
            float v0 = ba + ci * a0 + cj * a1 + ck * a2 + ft * a3;
            float v1 = bc + ci * c0 + cj * c1 + ck * c2 + ft * c3;
            ((unsigned*)(X + node * XP))[cp] = fpack2(v0, v1);
            sp0 += v0 * m; sp1 += v1 * m;
        }
        sred[wv * 128 + co0] = sp0;          // disjoint from fC (bytes 8K+)
        sred[wv * 128 + co1] = sp1;
    }
    __syncthreads();
    if (tid == 0) {
        float n = 0.f;
#pragma unroll
        for (int g = 0; g < 8; g++) n += scnt[g];
        invS = (n > 1.f) ? 1.f / (n - 1.f) : 0.f;
    }
    __syncthreads();
    if (tid < 128) {
        float s = 0.f;
#pragma unroll
        for (int g = 0; g < 16; g++) s += sred[g * 128 + tid];
        ssc[tid] = s * invS;
    }
    __syncthreads();
    // sbase = blv + ssc @ WlP : 8-way K-split over all 1024 threads
    {
        int part = tid >> 7, c = tid & 127;
        float a = 0.f;
#pragma unroll
        for (int k4 = part * 4; k4 < part * 4 + 4; k4++)
            a += dot4(*(const float4*)(ssc + k4 * 4), WlP[k4 * 384 + c]);
        sred[part * 128 + c] = a;
    }
    __syncthreads();
    if (tid < 128) {
        float a = blv[tid];
#pragma unroll
        for (int p = 0; p < 8; p++) a += sred[p * 128 + tid];
        sbase[tid] = a;
    }
    __syncthreads();

    float ninv = -invS;   // wave-uniform; constant across layers

// D_BUILD(H): build N-half H of D = Wr - inv*Wl into Ds (bf16 fragments).
// 1024 threads, 1024 items of 8 ushorts -> one item per thread.
#define D_BUILD(H)                                                            \
    {                                                                         \
        const ushort* wl = WB + ((size_t)(l * 2 + 0) * 32 + (H) * 16) * 512;  \
        const ushort* wr = WB + ((size_t)(l * 2 + 1) * 32 + (H) * 16) * 512;  \
        int g = tid;                                                          \
        uint4 ul = *(const uint4*)(wl + g * 8);                               \
        uint4 ur = *(const uint4*)(wr + g * 8);                               \
        uint4 d;                                                              \
        d.x = fpack2(fmaf(ninv, ulo(ul.x), ulo(ur.x)), fmaf(ninv, uhi(ul.x), uhi(ur.x))); \
        d.y = fpack2(fmaf(ninv, ulo(ul.y), ulo(ur.y)), fmaf(ninv, uhi(ul.y), uhi(ur.y))); \
        d.z = fpack2(fmaf(ninv, ulo(ul.z), ulo(ur.z)), fmaf(ninv, uhi(ul.z), uhi(ur.z))); \
        d.w = fpack2(fmaf(ninv, ulo(ul.w), ulo(ur.w)), fmaf(ninv, uhi(ul.w), uhi(ur.w))); \
        *(uint4*)(Ds + g * 8) = d;                                            \
    }

// GEMM8(OFF): acc[OFF..OFF+3] += 16-row x-tile @ Ds^T. OFF literal -> all
// acc indices compile-time (rule #20). Live set: a(4) + bg staged(16) +
// addressing — fits the 96-arch budget with 32-AGPR acc.
#define GEMM8(OFF)                                                            \
    _Pragma("unroll")                                                         \
    for (int ks = 0; ks < 4; ks++) {                                          \
        short8 a = *(const short8*)(xr + ks * 32);                            \
        short8 bg[4];                                                         \
        _Pragma("unroll")                                                     \
        for (int t = 0; t < 4; t++)                                           \
            bg[t] = *(const short8*)(Ds + (size_t)(t * 4 + ks) * 512 + lane * 8); \
        _Pragma("unroll")                                                     \
        for (int t = 0; t < 4; t++)                                           \
            acc[(OFF) + t] = __builtin_amdgcn_mfma_f32_16x16x32_bf16(a, bg[t], acc[(OFF) + t], 0, 0, 0); \
    }

    // ================= 3 SAGE layers (two 256-row phases each) ============
    for (int l = 0; l < 3; l++) {
        bool last = (l == 2);
        float sp[8];
#pragma unroll
        for (int t = 0; t < 8; t++) sp[t] = 0.f;

#pragma unroll 1
        for (int rp = 0; rp < 2; rp++) {
            f32x4 acc[8];   // 16 rows x 128 cols; 32 AGPRs
#pragma unroll
            for (int t = 0; t < 8; t++) acc[t] = (f32x4){0.f, 0.f, 0.f, 0.f};

            int rbase = rp * 256 + wv * 16;
            const ushort* xr = X + (rbase + ml) * XP + quad * 8;

            D_BUILD(0); __syncthreads(); GEMM8(0); __syncthreads();
            D_BUILD(1); __syncthreads(); GEMM8(4); __syncthreads();

            // epilogue for this 16-row phase: relu+base -> LN -> bf16 into X
#pragma unroll
            for (int r = 0; r < 4; r++) {
                int row = rbase + quad * 4 + r;
                float s = 0.f, q = 0.f;
#pragma unroll
                for (int t = 0; t < 8; t++) {
                    float vv = fmaxf(acc[t][r] + sbase[t * 16 + ml], 0.f);
                    acc[t][r] = vv;
                    s += vv; q = fmaf(vv, vv, q);
                }
#pragma unroll
                for (int off = 1; off <= 8; off <<= 1) {
                    s += __shfl_xor(s, off, 64);
                    q += __shfl_xor(q, off, 64);
                }
                float mu = s * (1.f / 128.f);
                float rs = rsqrtf(q * (1.f / 128.f) - mu * mu + EPSv);
                float mrow = u2f(mCu[row]);
                unsigned* xw = (unsigned*)(X + row * XP);
                if (last) {
#pragma unroll
                    for (int t2 = 0; t2 < 4; t2++) {
                        float y0 = ((acc[2*t2][r]   - mu) * rs * gln[(2*t2)*16 + ml]   + bln[(2*t2)*16 + ml])   * mrow;
                        float y1 = ((acc[2*t2+1][r] - mu) * rs * gln[(2*t2+1)*16 + ml] + bln[(2*t2+1)*16 + ml]) * mrow;
                        xw[t2 * 16 + ml] = fpack2(y0, y1);
                    }
                } else {
#pragma unroll
                    for (int t2 = 0; t2 < 4; t2++) {
                        float y0 = (acc[2*t2][r]   - mu) * rs * gln[(2*t2)*16 + ml]   + bln[(2*t2)*16 + ml];
                        float y1 = (acc[2*t2+1][r] - mu) * rs * gln[(2*t2+1)*16 + ml] + bln[(2*t2+1)*16 + ml];
                        sp[2*t2]   = fmaf(y0, mrow, sp[2*t2]);
                        sp[2*t2+1] = fmaf(y1, mrow, sp[2*t2+1]);
                        xw[t2 * 16 + ml] = fpack2(y0, y1);
                    }
                }
            }
        }

        if (!last) {
#pragma unroll
            for (int t = 0; t < 8; t++) {
                sp[t] += __shfl_xor(sp[t], 16, 64);
                sp[t] += __shfl_xor(sp[t], 32, 64);
            }
            if (quad == 0) {
#pragma unroll
                for (int t = 0; t < 8; t++) sred[wv * 128 + t * 16 + ml] = sp[t];
            }
            __syncthreads();
            if (tid < 128) {
                float s = 0.f;
#pragma unroll
                for (int g = 0; g < 16; g++) s += sred[g * 128 + tid];
                ssc[tid] = s * invS;
            }
            __syncthreads();
            {
                int part = tid >> 7, c = tid & 127;
                float a = 0.f;
#pragma unroll
                for (int k4 = part * 4; k4 < part * 4 + 4; k4++)
                    a += dot4(*(const float4*)(ssc + k4 * 4), WlP[k4 * 384 + (l + 1) * 128 + c]);
                sred[part * 128 + c] = a;
            }
            __syncthreads();
            if (tid < 128) {
                float a = blv[(l + 1) * 128 + tid];
#pragma unroll
                for (int p = 0; p < 8; p++) a += sred[p * 128 + tid];
                sbase[tid] = a;
            }
            __syncthreads();
        }
    }
    __syncthreads();

    // ================= pool: slice means (paired-channel layout) ==========
    if (tid < 768) {
        int c4 = tid & 31, p = tid >> 5;
        int axis = p >> 3, idx = p & 7;
        float4 sum = {0.f, 0.f, 0.f, 0.f};
        for (int t = 0; t < 64; t++) {
            int node;
            if (axis == 0)      node = idx * 64 + t;
            else if (axis == 1) node = (t >> 3) * 64 + idx * 8 + (t & 7);
            else                node = t * 8 + idx;
            uint2 pk = *(const uint2*)(X + node * XP + c4 * 4);
            sum.x += ulo(pk.x);   // ch E0
            sum.y += uhi(pk.x);   // ch E0+16
            sum.z += ulo(pk.y);   // ch E0+1
            sum.w += uhi(pk.y);   // ch E0+17
        }
        int E0 = 32 * (c4 >> 3) + 2 * (c4 & 7);
        float* ob = out + (size_t)b * 26 * Cc + p * Cc;
        float2 lo = {sum.x * (1.f / 64.f), sum.z * (1.f / 64.f)};
        float2 hi = {sum.y * (1.f / 64.f), sum.w * (1.f / 64.f)};
        *(float2*)(ob + E0)      = lo;
        *(float2*)(ob + E0 + 16) = hi;
    }
}

// ---------------------------------------------------------------------------
// k_tf3: transformer, bf16 MFMA GEMMs; q/k/v stored bf16 (~50 KB LDS).
// 512 threads, launch_bounds(512,4) guarantees <=128 regs/wave -> 2
// blocks/CU. LN stats+apply fused (one phase per LN). Attention on 480
// threads (8 lanes per (h,tq) pair, 3x shfl_xor reduce).
// ---------------------------------------------------------------------------
__global__ __launch_bounds__(512, 4) void k_tf3(
    const int* __restrict__ xx, const float* __restrict__ ss,
    const ushort* __restrict__ WactB, const float* __restrict__ bact,
    const ushort* __restrict__ WqkvB, const float* __restrict__ bqkv,
    const ushort* __restrict__ WoB, const float* __restrict__ bo,
    const float* __restrict__ ln1g, const float* __restrict__ ln1b,
    const float* __restrict__ ln2g, const float* __restrict__ ln2b,
    const ushort* __restrict__ W1B, const float* __restrict__ b1v,
    const ushort* __restrict__ W2B, const float* __restrict__ b2v,
    const float* __restrict__ Wsc, const float* __restrict__ bsc,
    float* __restrict__ out)
{
    __shared__ float  As[TT * 132];
    __shared__ ushort Qs[16 * 392];
    __shared__ ushort Ab[16 * 136];
    __shared__ ushort Hs[16 * 136];
    __shared__ ushort Fs[16 * 520];
    __shared__ float  Att[60 * 16];

    int b = blockIdx.x, tid = threadIdx.x;
    int wv = tid >> 6, lane = tid & 63;      // wv in 0..7
    int ml = lane & 15, quad = lane >> 4;

    const int* xa = xx + (size_t)b * Tsz * S3 + S3;
    {
        const int4* xa4 = (const int4*)xa;          // 15*512/4 = 1920
        for (int i = tid; i < 1920; i += 512) {
            int4 v = xa4[i];
            int t = i >> 7, s = (i & 127) << 2;     // 128 int4 per row
            ushort4 o;
            o.x = bfr16((float)v.x); o.y = bfr16((float)v.y);
            o.z = bfr16((float)v.z); o.w = bfr16((float)v.w);
            *(ushort4*)(Fs + t * 520 + s) = o;
        }
    }
    __syncthreads();

    // act embedding: N=128 -> 8 tiles, wave wv owns tile wv (K=512)
    {
        f32x4 acc = (f32x4){0.f, 0.f, 0.f, 0.f};
        const ushort* ar = Fs + ml * 520 + quad * 8;
        const ushort* wb = WactB + (size_t)(wv * 16 + ml) * 512 + quad * 8;
        for (int ks = 0; ks < 16; ks++) {
            short8 a   = *(const short8*)(ar + ks * 32);
            short8 bfr = *(const short8*)(wb + ks * 32);
            acc = __builtin_amdgcn_mfma_f32_16x16x32_bf16(a, bfr, acc, 0, 0, 0);
        }
        int col = wv * 16 + ml;
        float bb = bact[col];
#pragma unroll
        for (int r = 0; r < 4; r++) {
            int row = quad * 4 + r;
            if (row < TT) As[row * 132 + col] = acc[r] + bb;
        }
    }
    __syncthreads();

    for (int l = 0; l < 2; l++) {
        const float* bq  = bqkv + l * 384;
        const float* bol = bo + l * 128;
        const float* g1  = ln1g + l * 128; const float* be1 = ln1b + l * 128;
        const float* g2  = ln2g + l * 128; const float* be2 = ln2b + l * 128;
        const float* b1l = b1v + l * 512;  const float* b2l = b2v + l * 128;

        // LN1 fused (stats + apply + pack in one phase; wave r does rows
        // r, r+8; each lane owns 2 channels)
        for (int r = wv; r < TT; r += 8) {
            float2 v = *(const float2*)(As + r * 132 + lane * 2);
            float s = v.x + v.y, q = v.x * v.x + v.y * v.y;
            for (int off = 32; off; off >>= 1) {
                s += __shfl_xor(s, off, 64);
                q += __shfl_xor(q, off, 64);
            }
            float mu = s * (1.f / 128.f);
            float rs = rsqrtf(q * (1.f / 128.f) - mu * mu + EPSv);
            float x0 = (v.x - mu) * rs * g1[2 * lane]     + be1[2 * lane];
            float x1 = (v.y - mu) * rs * g1[2 * lane + 1] + be1[2 * lane + 1];
            ((unsigned*)(Ab + r * 136))[lane] = fpack2(x0, x1);
        }
        __syncthreads();

        // qkv (K=128, N=384 -> 24 tiles, 3 per wave) -> Qs bf16
        {
            short8 a[4];
            const ushort* ar = Ab + ml * 136 + quad * 8;
#pragma unroll
            for (int ks = 0; ks < 4; ks++) a[ks] = *(const short8*)(ar + ks * 32);
#pragma unroll
            for (int i = 0; i < 3; i++) {
                int n0 = (wv * 3 + i) * 16;
                f32x4 acc = (f32x4){0.f, 0.f, 0.f, 0.f};
                const ushort* wb = WqkvB + (size_t)(l * 384 + n0 + ml) * 128 + quad * 8;
#pragma unroll
                for (int ks = 0; ks < 4; ks++) {
                    short8 bfr = *(const short8*)(wb + ks * 32);
                    acc = __builtin_amdgcn_mfma_f32_16x16x32_bf16(a[ks], bfr, acc, 0, 0, 0);
                }
                int col = n0 + ml;
                float bb = bq[col];
#pragma unroll
                for (int r = 0; r < 4; r++) {
                    int row = quad * 4 + r;
                    if (row < TT) Qs[row * 392 + col] = bfr16(acc[r] + bb);
                }
            }
        }
        __syncthreads();

        // attention scores + softmax: 480 threads, 8 lanes per (h,tq) pair,
        // each lane 4 channels; 3x shfl_xor sums the eighths.
        if (tid < 480) {
            int pair = tid >> 3, part = tid & 7;
            int h = pair / 15, tq = pair % 15;
            const ushort* qp = Qs + tq * 392 + h * 32 + part * 4;
            float sc[TT];
#pragma unroll
            for (int tk = 0; tk < TT; tk++) {
                const ushort* kp = Qs + tk * 392 + 128 + h * 32 + part * 4;
                uint2 qa = *(const uint2*)(qp);
                uint2 ka = *(const uint2*)(kp);
                float d = ulo(qa.x) * ulo(ka.x) + uhi(qa.x) * uhi(ka.x)
                        + ulo(qa.y) * ulo(ka.y) + uhi(qa.y) * uhi(ka.y);
                d += __shfl_xor(d, 1, 64);
                d += __shfl_xor(d, 2, 64);
                d += __shfl_xor(d, 4, 64);
                sc[tk] = d * 0.17677669529663689f;
            }
            if (part == 0) {
                float mx = -1e30f;
#pragma unroll
                for (int tk = 0; tk < TT; tk++) mx = fmaxf(mx, sc[tk]);
                float sum = 0.f;
#pragma unroll
                for (int tk = 0; tk < TT; tk++) { float e = __expf(sc[tk] - mx); sc[tk] = e; sum += e; }
                float r = 1.f / sum;
#pragma unroll
                for (int tk = 0; tk < TT; tk++) Att[pair * 16 + tk] = sc[tk] * r;
            }
        }
        __syncthreads();

        // o = att @ v -> Hs (bf16)
        for (int f = tid; f < TT * 64; f += 512) {
            int t = f >> 6, cp = f & 63;
            int h = cp >> 4;
            const float* ap = Att + (h * 15 + t) * 16;
            const ushort* vp = Qs + 256 + 2 * cp;
            float a0 = 0.f, a1 = 0.f;
#pragma unroll
            for (int tk = 0; tk < TT; tk++) {
                float w = ap[tk];
                unsigned pk = *(const unsigned*)(vp + tk * 392);
                a0 += w * ulo(pk);
                a1 += w * uhi(pk);
            }
            ((unsigned*)(Hs + t * 136))[cp] = fpack2(a0, a1);
        }
        __syncthreads();

        // proj + residual: N=128 -> 8 tiles, 1 per wave
        {
            short8 a[4];
            const ushort* ar = Hs + ml * 136 + quad * 8;
#pragma unroll
            for (int ks = 0; ks < 4; ks++) a[ks] = *(const short8*)(ar + ks * 32);
            int n0 = wv * 16;
            f32x4 acc = (f32x4){0.f, 0.f, 0.f, 0.f};
            const ushort* wb = WoB + (size_t)(l * 128 + n0 + ml) * 128 + quad * 8;
#pragma unroll
            for (int ks = 0; ks < 4; ks++) {
                short8 bfr = *(const short8*)(wb + ks * 32);
                acc = __builtin_amdgcn_mfma_f32_16x16x32_bf16(a[ks], bfr, acc, 0, 0, 0);
            }
            int col = n0 + ml;
            float bb = bol[col];
#pragma unroll
            for (int r = 0; r < 4; r++) {
                int row = quad * 4 + r;
                if (row < TT) As[row * 132 + col] += acc[r] + bb;
            }
        }
        __syncthreads();

        // LN2 fused
        for (int r = wv; r < TT; r += 8) {
            float2 v = *(const float2*)(As + r * 132 + lane * 2);
            float s = v.x + v.y, q = v.x * v.x + v.y * v.y;
            for (int off = 32; off; off >>= 1) {
                s += __shfl_xor(s, off, 64);
                q += __shfl_xor(q, off, 64);
            }
            float mu = s * (1.f / 128.f);
            float rs = rsqrtf(q * (1.f / 128.f) - mu * mu + EPSv);
            float x0 = (v.x - mu) * rs * g2[2 * lane]     + be2[2 * lane];
            float x1 = (v.y - mu) * rs * g2[2 * lane + 1] + be2[2 * lane + 1];
            ((unsigned*)(Ab + r * 136))[lane] = fpack2(x0, x1);
        }
        __syncthreads();

        // ff1 (K=128, N=512 -> 32 tiles, 4 per wave)
        {
            short8 a[4];
            const ushort* ar = Ab + ml * 136 + quad * 8;
#pragma unroll
            for (int ks = 0; ks < 4; ks++) a[ks] = *(const short8*)(ar + ks * 32);
#pragma unroll
            for (int i = 0; i < 4; i++) {
                int n0 = (wv * 4 + i) * 16;
                f32x4 acc = (f32x4){0.f, 0.f, 0.f, 0.f};
                const ushort* wb = W1B + (size_t)(l * 512 + n0 + ml) * 128 + quad * 8;
#pragma unroll
                for (int ks = 0; ks < 4; ks++) {
                    short8 bfr = *(const short8*)(wb + ks * 32);
                    acc = __builtin_amdgcn_mfma_f32_16x16x32_bf16(a[ks], bfr, acc, 0, 0, 0);
                }
                int col = n0 + ml;
                float bb = b1l[col];
#pragma unroll
                for (int r = 0; r < 4; r++) {
                    int row = quad * 4 + r;
                    if (row < TT) Fs[row * 520 + col] = bfr16(fmaxf(acc[r] + bb, 0.f));
                }
            }
        }
        __syncthreads();

        // ff2 + residual (K=512, N=128 -> 8 tiles, 1 per wave)
        {
            f32x4 acc = (f32x4){0.f, 0.f, 0.f, 0.f};
            const ushort* ar = Fs + ml * 520 + quad * 8;
            int n0 = wv * 16;
            const ushort* wb = W2B + (size_t)(l * 128 + n0 + ml) * 512 + quad * 8;
            for (int ks = 0; ks < 16; ks++) {
                short8 a   = *(const short8*)(ar + ks * 32);
                short8 bfr = *(const short8*)(wb + ks * 32);
                acc = __builtin_amdgcn_mfma_f32_16x16x32_bf16(a, bfr, acc, 0, 0, 0);
            }
            int col = n0 + ml;
            float bb = b2l[col];
#pragma unroll
            for (int r = 0; r < 4; r++) {
                int row = quad * 4 + r;
                if (row < TT) As[row * 132 + col] += acc[r] + bb;
            }
        }
        __syncthreads();
    }

    if (tid < 128) {
        float s = 0.f;
#pragma unroll
        for (int t = 0; t < TT; t++) s += As[t * 132 + tid];
        out[(size_t)b * 26 * Cc + 24 * Cc + tid] = s * (1.f / 15.f);
    } else if (tid < 256) {
        int co = tid - 128;
        float v = ss[b] * Wsc[co] + bsc[co];
        out[(size_t)b * 26 * Cc + 25 * Cc + co] = fmaxf(v, 0.f);
    }
}

// ---------------------------------------------------------------------------
extern "C" void kernel_launch(void* const* d_in, const int* in_sizes, int n_in,
                              void* d_out, int out_size, void* d_ws, size_t ws_size,
                              hipStream_t stream)
{
    (void)in_sizes; (void)n_in; (void)out_size; (void)ws_size;
    const int*   xx   = (const int*)d_in[0];
    const float* ss   = (const float*)d_in[1];
    const float* Win  = (const float*)d_in[2];
    const float* b_in = (const float*)d_in[3];
    const float* Wl   = (const float*)d_in[4];
    const float* bl   = (const float*)d_in[5];
    const float* Wr   = (const float*)d_in[6];
    const float* lng  = (const float*)d_in[7];
    const float* lnb  = (const float*)d_in[8];
    const float* Wqkv = (const float*)d_in[9];
    const float* bqkv = (const float*)d_in[10];
    const float* Wo   = (const float*)d_in[11];
    const float* bo   = (const float*)d_in[12];
    const float* ln1g = (const float*)d_in[13];
    const float* ln1b = (const float*)d_in[14];
    const float* ln2g = (const float*)d_in[15];
    const float* ln2b = (const float*)d_in[16];
    const float* W1   = (const float*)d_in[17];
    const float* b1   = (const float*)d_in[18];
    const float* W2   = (const float*)d_in[19];
    const float* b2   = (const float*)d_in[20];
    const float* Wact = (const float*)d_in[21];
    const float* bact = (const float*)d_in[22];
    const float* Wsc  = (const float*)d_in[23];
    const float* bsc  = (const float*)d_in[24];
    float* out = (float*)d_out;

    char* ws = (char*)d_ws;
    size_t off = 0;
    float* WlT  = (float*)(ws + off); off += 384 * 128 * 4;
    ushort* WB    = (ushort*)(ws + off); off += (size_t)3 * 2 * 128 * 128 * 2;
    ushort* WactB = (ushort*)(ws + off); off += 128 * 512 * 2;
    ushort* WqkvB = (ushort*)(ws + off); off += 768 * 128 * 2;
    ushort* WoB   = (ushort*)(ws + off); off += 256 * 128 * 2;
    ushort* W1B   = (ushort*)(ws + off); off += 1024 * 128 * 2;
    ushort* W2B   = (ushort*)(ws + off); off += 256 * 512 * 2;

    k_tpack<<<dim3(4, 12), 256, 0, stream>>>(Wl, WlT, 384, 128);
    k_cvt5<<<448, 256, 0, stream>>>(Wact, Wqkv, Wo, W1, W2, WactB);
    k_wpack<<<dim3(3, 2), 256, 0, stream>>>(Wl, Wr, WB);

    k_torso<<<Bsz, 1024, 0, stream>>>(xx, ss, Win, b_in, WB,
                                      (const float4*)WlT, bl, lng, lnb, out);

    k_tf3<<<Bsz, 512, 0, stream>>>(xx, ss,
                                   WactB, bact, WqkvB, bqkv, WoB, bo,
                                   ln1g, ln1b, ln2g, ln2b,
                                   W1B, b1, W2B, b2,
                                   Wsc, bsc, out);
}

// Round 12
// 273.776 us; speedup vs baseline: 1.0321x; 1.0289x over previous
//
#include <hip/hip_runtime.h>
#include <hip/hip_bf16.h>
#include <string.h>

typedef __hip_bfloat16 bf16;
typedef __attribute__((ext_vector_type(8))) short short8;
typedef __attribute__((ext_vector_type(4))) float f32x4;

#define Bsz 512
#define S3  512
#define Tsz 16
#define Cc  128
#define TT  15
#define XP  136   // X row stride in ushorts (272B = 16B-aligned rows)
#define EPSv 1e-5f

__device__ __forceinline__ float u2f(unsigned short u) {
    return __uint_as_float(((unsigned)u) << 16);
}
__device__ __forceinline__ float ulo(unsigned u) { return __uint_as_float(u << 16); }
__device__ __forceinline__ float uhi(unsigned u) { return __uint_as_float(u & 0xffff0000u); }
__device__ __forceinline__ unsigned short f2bu(float v) {
    bf16 h = __float2bfloat16(v);
    unsigned short u; memcpy(&u, &h, 2); return u;
}
// fast RNE bf16 (no NaN path — inputs finite)
__device__ __forceinline__ unsigned short bfr16(float a) {
    unsigned u = __float_as_uint(a);
    u = u + 0x7fffu + ((u >> 16) & 1u);
    return (unsigned short)(u >> 16);
}
// HW packed f32x2 -> bf16x2 (RNE), one VALU op. lo = a, hi = b.
__device__ __forceinline__ unsigned fpack2(float a, float b) {
    unsigned r;
    asm("v_cvt_pk_bf16_f32 %0, %1, %2" : "=v"(r) : "v"(a), "v"(b));
    return r;
}
__device__ __forceinline__ float dot4(float4 a, float4 b) {
    return a.x*b.x + a.y*b.y + a.z*b.z + a.w*b.w;
}

// ---------------------------------------------------------------------------
// X channel layout (k_torso): row-major 512 x 68 dwords; dword slot
// s = t2*16 + ml holds orig channels (32*t2 + ml) lo, (32*t2 + 16 + ml) hi —
// the two channels one MFMA C-lane owns, so LN packs via one cvt_pk.
// k_prep's wpack part interleaves the weight K-dim to match; N-dim identity.
// ---------------------------------------------------------------------------

// ---------------------------------------------------------------------------
// k_prep: ALL weight preprocessing in one launch (was 3 kernels — merged to
// cut launch count; the timed graph's fixed overhead scales with dispatches).
//  blocks [0,48):    tpack  — Wl (384x128 fp32) -> float4-packed k-major WlT
//  blocks [48,496):  cvt5   — 5 transformer weights fp32 -> bf16 (contiguous)
//  blocks [496,502): wpack  — Wl/Wr -> bf16 MFMA-fragment-major WB,
//                    K-interleaved to X's paired-channel layout:
//                    frag elem j of (ks,q) <- col 32*ks + q*4 + (j>>1) + 16*(j&1)
// ---------------------------------------------------------------------------
__global__ __launch_bounds__(256) void k_prep(
    const float* __restrict__ Wl, const float* __restrict__ Wr,
    float* __restrict__ WlT,
    const float* __restrict__ s0, const float* __restrict__ s1,
    const float* __restrict__ s2, const float* __restrict__ s3,
    const float* __restrict__ s4, ushort* __restrict__ cvtdst,
    ushort* __restrict__ WB)
{
    __shared__ float tile[32][33];
    int bid = blockIdx.x;
    if (bid < 48) {
        // ---- tpack (NR=384, NK=128) ----
        const int NR = 384, NK = 128;
        int k0 = (bid & 3) * 32, r0 = (bid >> 2) * 32;
        int lr = threadIdx.x >> 5, lk = threadIdx.x & 31;
        for (int i = lr; i < 32; i += 8)
            tile[i][lk] = Wl[(size_t)(r0 + i) * NK + k0 + lk];
        __syncthreads();
        int c = threadIdx.x & 31, k4 = threadIdx.x >> 5;
        float4 v;
        v.x = tile[c][k4 * 4 + 0]; v.y = tile[c][k4 * 4 + 1];
        v.z = tile[c][k4 * 4 + 2]; v.w = tile[c][k4 * 4 + 3];
        ((float4*)WlT)[(size_t)(k0 / 4 + k4) * NR + r0 + c] = v;
    } else if (bid < 496) {
        // ---- cvt5 ----
        int i = (bid - 48) * 256 + threadIdx.x;
        if (i >= 114688) return;
        const float* src; int rel;
        if (i < 16384)      { src = s0; rel = i; }
        else if (i < 40960) { src = s1; rel = i - 16384; }
        else if (i < 49152) { src = s2; rel = i - 40960; }
        else if (i < 81920) { src = s3; rel = i - 49152; }
        else                { src = s4; rel = i - 81920; }
        float4 v = ((const float4*)src)[rel];
        ushort4 o;
        o.x = f2bu(v.x); o.y = f2bu(v.y); o.z = f2bu(v.z); o.w = f2bu(v.w);
        ((ushort4*)cvtdst)[i] = o;
    } else {
        // ---- wpack ----
        int t6 = bid - 496;
        int l = t6 % 3, w = t6 / 3;
        const float* src = (w == 0 ? Wl : Wr) + l * 16384;
        ushort* dst = WB + (size_t)(l * 2 + w) * 32 * 512;
        for (int item = threadIdx.x; item < 2048; item += 256) {
            int f = item >> 6, lane = item & 63;
            int t = f >> 2, ks = f & 3, ml = lane & 15, q = lane >> 4;
            int n = t * 16 + ml;
            const float* sA = src + n * 128 + 32 * ks + q * 4;
            const float* sB = sA + 16;
            float4 a = *(const float4*)sA;
            float4 b = *(const float4*)sB;
            ushort4 o0, o1;
            o0.x = f2bu(a.x); o0.y = f2bu(b.x); o0.z = f2bu(a.y); o0.w = f2bu(b.y);
            o1.x = f2bu(a.z); o1.y = f2bu(b.z); o1.z = f2bu(a.w); o1.w = f2bu(b.w);
            ushort* dp = dst + (size_t)f * 512 + lane * 8;
            *(ushort4*)dp = o0;
            *(ushort4*)(dp + 4) = o1;
        }
    }
}

// ---------------------------------------------------------------------------
// k_torso: fused init + 3 GNN layers + pool. 1024 threads (16 waves,
// 4 waves/SIMD). Wave wv owns rows [wv*32,wv*32+32); acc[8][2] = 64 AGPRs.
// ROUND-12 NOTE: this is the round-8 source restored VERBATIM — the fastest
// measured variant (110.3 µs). It spills ~27 dwords/thread (57 MB WRITE)
// at the exactly-full 128-reg/wave budget; rounds 9-11 proved eliminating
// that spill (via LDS-reads, sp-placement, or row-phasing) costs MORE than
// the spill itself — the scratch stores are fire-and-forget and fully
// latency-hidden, while the fixes added barriers/D_BUILDs/LDS latency.
// D = Wr - inv*Wl built per layer into LDS one 16KB N-half at a time
// (straight-line macros, compile-time acc indices per rule #20); GEMM B via
// ds_read_b128. sred aliased into upper half of Ds; fC aliases its first
// 2KB. LDS 158788 <= 163840 -> 1 block/CU, 16 waves.
// ---------------------------------------------------------------------------
__global__ __launch_bounds__(1024) void k_torso(
    const int* __restrict__ xx, const float* __restrict__ ss,
    const float* __restrict__ Win, const float* __restrict__ b_in,
    const ushort* __restrict__ WB,
    const float4* __restrict__ WlP, const float* __restrict__ blv,
    const float* __restrict__ lng, const float* __restrict__ lnb,
    float* __restrict__ out)
{
    __shared__ ushort X[512 * XP];
    __shared__ ushort Ds[16 * 512];        // one N-half of D, fragment-major
    __shared__ ushort mCu[512];            // node mask as bf16 (1.0 / 0.0)
    __shared__ float  ssc[128];
    __shared__ float  sbase[128];
    __shared__ float  gln[128], bln[128];
    __shared__ float  scnt[8];
    __shared__ float  invS;

    int b = blockIdx.x, tid = threadIdx.x;
    int wv = tid >> 6, lane = tid & 63;      // wv in 0..15
    int ml = lane & 15, quad = lane >> 4;

    int*   fC   = (int*)Ds;                  // bytes [0, 2048): frame0 staging
    float* sred = (float*)(Ds + 4096);       // bytes [8192, 16384): 16x128 f32

    // ================= stage frame0 + mask + count =================
    const int* x0 = xx + (size_t)b * Tsz * S3;
    if (tid < 512) {
        int f0 = x0[tid];                    // coalesced, one per thread
        fC[tid] = f0;
        mCu[tid] = (f0 != 0) ? (ushort)0x3F80 : (ushort)0;
        unsigned long long bal = __ballot(f0 != 0);
        if (lane == 0) scnt[wv] = (float)__popcll(bal);
    }
    if (tid < 128) { gln[tid] = lng[tid]; bln[tid] = lnb[tid]; }
    __syncthreads();

    // ================= init features =================
    {
        int cp = lane;
        // slot cp holds orig channels (co0, co0+16)
        int co0 = 32 * (cp >> 4) + (cp & 15), co1 = co0 + 16;
        float f4c = ss[b] * (1.0f / 8.0f);
        float a0 = Win[co0*5+0], a1 = Win[co0*5+1], a2 = Win[co0*5+2], a3 = Win[co0*5+3];
        float c0 = Win[co1*5+0], c1 = Win[co1*5+1], c2 = Win[co1*5+2], c3 = Win[co1*5+3];
        float ba = b_in[co0] + f4c * Win[co0*5+4];
        float bc = b_in[co1] + f4c * Win[co1*5+4];
        float sp0 = 0.f, sp1 = 0.f;
        for (int node = wv; node < S3; node += 16) {
            int f0 = fC[node];               // LDS broadcast
            float m = (f0 != 0) ? 1.f : 0.f;
            float ci = (float)(node >> 6) * (1.f / 7.f);
            float cj = (float)((node >> 3) & 7) * (1.f / 7.f);
            float ck = (float)(node & 7) * (1.f / 7.f);
            float ft = (float)f0 * 0.5f;
            float v0 = ba + ci * a0 + cj * a1 + ck * a2 + ft * a3;
            float v1 = bc + ci * c0 + cj * c1 + ck * c2 + ft * c3;
            ((unsigned*)(X + node * XP))[cp] = fpack2(v0, v1);
            sp0 += v0 * m; sp1 += v1 * m;
        }
        sred[wv * 128 + co0] = sp0;          // disjoint from fC (bytes 8K+)
        sred[wv * 128 + co1] = sp1;
    }
    __syncthreads();
    if (tid == 0) {
        float n = 0.f;
#pragma unroll
        for (int g = 0; g < 8; g++) n += scnt[g];
        invS = (n > 1.f) ? 1.f / (n - 1.f) : 0.f;
    }
    __syncthreads();
    if (tid < 128) {
        float s = 0.f;
#pragma unroll
        for (int g = 0; g < 16; g++) s += sred[g * 128 + tid];
        ssc[tid] = s * invS;
    }
    __syncthreads();
    // sbase = blv + ssc @ WlP : 8-way K-split over all 1024 threads
    {
        int part = tid >> 7, c = tid & 127;
        float a = 0.f;
#pragma unroll
        for (int k4 = part * 4; k4 < part * 4 + 4; k4++)
            a += dot4(*(const float4*)(ssc + k4 * 4), WlP[k4 * 384 + c]);
        sred[part * 128 + c] = a;
    }
    __syncthreads();
    if (tid < 128) {
        float a = blv[tid];
#pragma unroll
        for (int p = 0; p < 8; p++) a += sred[p * 128 + tid];
        sbase[tid] = a;
    }
    __syncthreads();

    float ninv = -invS;   // wave-uniform; constant across layers

// D_BUILD(H): build N-half H of D = Wr - inv*Wl into Ds (bf16 fragments).
// 1024 threads, 1024 items of 8 ushorts -> one item per thread.
#define D_BUILD(H)                                                            \
    {                                                                         \
        const ushort* wl = WB + ((size_t)(l * 2 + 0) * 32 + (H) * 16) * 512;  \
        const ushort* wr = WB + ((size_t)(l * 2 + 1) * 32 + (H) * 16) * 512;  \
        int g = tid;                                                          \
        uint4 ul = *(const uint4*)(wl + g * 8);                               \
        uint4 ur = *(const uint4*)(wr + g * 8);                               \
        uint4 d;                                                              \
        d.x = fpack2(fmaf(ninv, ulo(ul.x), ulo(ur.x)), fmaf(ninv, uhi(ul.x), uhi(ur.x))); \
        d.y = fpack2(fmaf(ninv, ulo(ul.y), ulo(ur.y)), fmaf(ninv, uhi(ul.y), uhi(ur.y))); \
        d.z = fpack2(fmaf(ninv, ulo(ul.z), ulo(ur.z)), fmaf(ninv, uhi(ul.z), uhi(ur.z))); \
        d.w = fpack2(fmaf(ninv, ulo(ul.w), ulo(ur.w)), fmaf(ninv, uhi(ul.w), uhi(ur.w))); \
        *(uint4*)(Ds + g * 8) = d;                                            \
    }

// GEMM_HALF(OFF): acc[OFF..OFF+3] += x-tile @ Ds^T. OFF literal -> all acc
// indices compile-time (rule #20).
#define GEMM_HALF(OFF)                                                        \
    _Pragma("unroll")                                                         \
    for (int ks = 0; ks < 4; ks++) {                                          \
        short8 a0 = *(const short8*)(xr0 + ks * 32);                          \
        short8 a1 = *(const short8*)(xr1 + ks * 32);                          \
        short8 bg[4];                                                         \
        _Pragma("unroll")                                                     \
        for (int t = 0; t < 4; t++)                                           \
            bg[t] = *(const short8*)(Ds + (size_t)(t * 4 + ks) * 512 + lane * 8); \
        _Pragma("unroll")                                                     \
        for (int t = 0; t < 4; t++) {                                         \
            acc[(OFF) + t][0] = __builtin_amdgcn_mfma_f32_16x16x32_bf16(a0, bg[t], acc[(OFF) + t][0], 0, 0, 0); \
            acc[(OFF) + t][1] = __builtin_amdgcn_mfma_f32_16x16x32_bf16(a1, bg[t], acc[(OFF) + t][1], 0, 0, 0); \
        }                                                                     \
    }

    // ================= 3 SAGE layers =================
    for (int l = 0; l < 3; l++) {
        bool last = (l == 2);
        float sp[8];
#pragma unroll
        for (int t = 0; t < 8; t++) sp[t] = 0.f;

        f32x4 acc[8][2];   // [n-tile][m-subtile]: 32 rows x 128 cols per wave
#pragma unroll
        for (int t = 0; t < 8; t++)
#pragma unroll
            for (int mm = 0; mm < 2; mm++) acc[t][mm] = (f32x4){0.f, 0.f, 0.f, 0.f};

        const ushort* xr0 = X + (wv * 32 + ml) * XP + quad * 8;
        const ushort* xr1 = xr0 + 16 * XP;

        // two N-halves, straight-line (compile-time acc indices):
        D_BUILD(0); __syncthreads(); GEMM_HALF(0); __syncthreads();
        D_BUILD(1); __syncthreads(); GEMM_HALF(4); __syncthreads();

        // epilogue: relu+base -> LN (shuffle stats) -> paired bf16 into X
        float bse[8], gg[8], be[8];
#pragma unroll
        for (int t = 0; t < 8; t++) {
            bse[t] = sbase[t * 16 + ml];
            gg[t]  = gln[t * 16 + ml];
            be[t]  = bln[t * 16 + ml];
        }
#pragma unroll
        for (int mm = 0; mm < 2; mm++) {
#pragma unroll
            for (int r = 0; r < 4; r++) {
                int row = wv * 32 + mm * 16 + quad * 4 + r;
                float s = 0.f, q = 0.f;
#pragma unroll
                for (int t = 0; t < 8; t++) {
                    float vv = fmaxf(acc[t][mm][r] + bse[t], 0.f);
                    acc[t][mm][r] = vv;
                    s += vv; q = fmaf(vv, vv, q);
                }
#pragma unroll
                for (int off = 1; off <= 8; off <<= 1) {
                    s += __shfl_xor(s, off, 64);
                    q += __shfl_xor(q, off, 64);
                }
                float mu = s * (1.f / 128.f);
                float rs = rsqrtf(q * (1.f / 128.f) - mu * mu + EPSv);
                float mrow = u2f(mCu[row]);
                unsigned* xr32 = (unsigned*)(X + row * XP);
                if (last) {
#pragma unroll
                    for (int t2 = 0; t2 < 4; t2++) {
                        float y0 = ((acc[2*t2][mm][r]   - mu) * rs * gg[2*t2]   + be[2*t2])   * mrow;
                        float y1 = ((acc[2*t2+1][mm][r] - mu) * rs * gg[2*t2+1] + be[2*t2+1]) * mrow;
                        xr32[t2 * 16 + ml] = fpack2(y0, y1);
                    }
                } else {
#pragma unroll
                    for (int t2 = 0; t2 < 4; t2++) {
                        float y0 = (acc[2*t2][mm][r]   - mu) * rs * gg[2*t2]   + be[2*t2];
                        float y1 = (acc[2*t2+1][mm][r] - mu) * rs * gg[2*t2+1] + be[2*t2+1];
                        sp[2*t2]   = fmaf(y0, mrow, sp[2*t2]);
                        sp[2*t2+1] = fmaf(y1, mrow, sp[2*t2+1]);
                        xr32[t2 * 16 + ml] = fpack2(y0, y1);
                    }
                }
            }
        }

        if (!last) {
#pragma unroll
            for (int t = 0; t < 8; t++) {
                sp[t] += __shfl_xor(sp[t], 16, 64);
                sp[t] += __shfl_xor(sp[t], 32, 64);
            }
            if (quad == 0) {
#pragma unroll
                for (int t = 0; t < 8; t++) sred[wv * 128 + t * 16 + ml] = sp[t];
            }
            __syncthreads();
            if (tid < 128) {
                float s = 0.f;
#pragma unroll
                for (int g = 0; g < 16; g++) s += sred[g * 128 + tid];
                ssc[tid] = s * invS;
            }
            __syncthreads();
            {
                int part = tid >> 7, c = tid & 127;
                float a = 0.f;
#pragma unroll
                for (int k4 = part * 4; k4 < part * 4 + 4; k4++)
                    a += dot4(*(const float4*)(ssc + k4 * 4), WlP[k4 * 384 + (l + 1) * 128 + c]);
                sred[part * 128 + c] = a;
            }
            __syncthreads();
            if (tid < 128) {
                float a = blv[(l + 1) * 128 + tid];
#pragma unroll
                for (int p = 0; p < 8; p++) a += sred[p * 128 + tid];
                sbase[tid] = a;
            }
            __syncthreads();
        }
    }
    __syncthreads();

    // ================= pool: slice means (paired-channel layout) ==========
    if (tid < 768) {
        int c4 = tid & 31, p = tid >> 5;
        int axis = p >> 3, idx = p & 7;
        float4 sum = {0.f, 0.f, 0.f, 0.f};
        for (int t = 0; t < 64; t++) {
            int node;
            if (axis == 0)      node = idx * 64 + t;
            else if (axis == 1) node = (t >> 3) * 64 + idx * 8 + (t & 7);
            else                node = t * 8 + idx;
            uint2 pk = *(const uint2*)(X + node * XP + c4 * 4);
            sum.x += ulo(pk.x);   // ch E0
            sum.y += uhi(pk.x);   // ch E0+16
            sum.z += ulo(pk.y);   // ch E0+1
            sum.w += uhi(pk.y);   // ch E0+17
        }
        int E0 = 32 * (c4 >> 3) + 2 * (c4 & 7);
        float* ob = out + (size_t)b * 26 * Cc + p * Cc;
        float2 lo = {sum.x * (1.f / 64.f), sum.z * (1.f / 64.f)};
        float2 hi = {sum.y * (1.f / 64.f), sum.w * (1.f / 64.f)};
        *(float2*)(ob + E0)      = lo;
        *(float2*)(ob + E0 + 16) = hi;
    }
}

// ---------------------------------------------------------------------------
// k_tf3: transformer, bf16 MFMA GEMMs; q/k/v stored bf16 (~50 KB LDS).
// 512 threads, launch_bounds(512,4) guarantees <=128 regs/wave -> 2
// blocks/CU. LN stats+apply fused (one phase per LN). Attention on 480
// threads (8 lanes per (h,tq) pair, 3x shfl_xor reduce). [round-11 version]
// ---------------------------------------------------------------------------
__global__ __launch_bounds__(512, 4) void k_tf3(
    const int* __restrict__ xx, const float* __restrict__ ss,
    const ushort* __restrict__ WactB, const float* __restrict__ bact,
    const ushort* __restrict__ WqkvB, const float* __restrict__ bqkv,
    const ushort* __restrict__ WoB, const float* __restrict__ bo,
    const float* __restrict__ ln1g, const float* __restrict__ ln1b,
    const float* __restrict__ ln2g, const float* __restrict__ ln2b,
    const ushort* __restrict__ W1B, const float* __restrict__ b1v,
    const ushort* __restrict__ W2B, const float* __restrict__ b2v,
    const float* __restrict__ Wsc, const float* __restrict__ bsc,
    float* __restrict__ out)
{
    __shared__ float  As[TT * 132];
    __shared__ ushort Qs[16 * 392];
    __shared__ ushort Ab[16 * 136];
    __shared__ ushort Hs[16 * 136];
    __shared__ ushort Fs[16 * 520];
    __shared__ float  Att[60 * 16];

    int b = blockIdx.x, tid = threadIdx.x;
    int wv = tid >> 6, lane = tid & 63;      // wv in 0..7
    int ml = lane & 15, quad = lane >> 4;

    const int* xa = xx + (size_t)b * Tsz * S3 + S3;
    {
        const int4* xa4 = (const int4*)xa;          // 15*512/4 = 1920
        for (int i = tid; i < 1920; i += 512) {
            int4 v = xa4[i];
            int t = i >> 7, s = (i & 127) << 2;     // 128 int4 per row
            ushort4 o;
            o.x = bfr16((float)v.x); o.y = bfr16((float)v.y);
            o.z = bfr16((float)v.z); o.w = bfr16((float)v.w);
            *(ushort4*)(Fs + t * 520 + s) = o;
        }
    }
    __syncthreads();

    // act embedding: N=128 -> 8 tiles, wave wv owns tile wv (K=512)
    {
        f32x4 acc = (f32x4){0.f, 0.f, 0.f, 0.f};
        const ushort* ar = Fs + ml * 520 + quad * 8;
        const ushort* wb = WactB + (size_t)(wv * 16 + ml) * 512 + quad * 8;
        for (int ks = 0; ks < 16; ks++) {
            short8 a   = *(const short8*)(ar + ks * 32);
            short8 bfr = *(const short8*)(wb + ks * 32);
            acc = __builtin_amdgcn_mfma_f32_16x16x32_bf16(a, bfr, acc, 0, 0, 0);
        }
        int col = wv * 16 + ml;
        float bb = bact[col];
#pragma unroll
        for (int r = 0; r < 4; r++) {
            int row = quad * 4 + r;
            if (row < TT) As[row * 132 + col] = acc[r] + bb;
        }
    }
    __syncthreads();

    for (int l = 0; l < 2; l++) {
        const float* bq  = bqkv + l * 384;
        const float* bol = bo + l * 128;
        const float* g1  = ln1g + l * 128; const float* be1 = ln1b + l * 128;
        const float* g2  = ln2g + l * 128; const float* be2 = ln2b + l * 128;
        const float* b1l = b1v + l * 512;  const float* b2l = b2v + l * 128;

        // LN1 fused (stats + apply + pack in one phase)
        for (int r = wv; r < TT; r += 8) {
            float2 v = *(const float2*)(As + r * 132 + lane * 2);
            float s = v.x + v.y, q = v.x * v.x + v.y * v.y;
            for (int off = 32; off; off >>= 1) {
                s += __shfl_xor(s, off, 64);
                q += __shfl_xor(q, off, 64);
            }
            float mu = s * (1.f / 128.f);
            float rs = rsqrtf(q * (1.f / 128.f) - mu * mu + EPSv);
            float x0 = (v.x - mu) * rs * g1[2 * lane]     + be1[2 * lane];
            float x1 = (v.y - mu) * rs * g1[2 * lane + 1] + be1[2 * lane + 1];
            ((unsigned*)(Ab + r * 136))[lane] = fpack2(x0, x1);
        }
        __syncthreads();

        // qkv (K=128, N=384 -> 24 tiles, 3 per wave) -> Qs bf16
        {
            short8 a[4];
            const ushort* ar = Ab + ml * 136 + quad * 8;
#pragma unroll
            for (int ks = 0; ks < 4; ks++) a[ks] = *(const short8*)(ar + ks * 32);
#pragma unroll
            for (int i = 0; i < 3; i++) {
                int n0 = (wv * 3 + i) * 16;
                f32x4 acc = (f32x4){0.f, 0.f, 0.f, 0.f};
                const ushort* wb = WqkvB + (size_t)(l * 384 + n0 + ml) * 128 + quad * 8;
#pragma unroll
                for (int ks = 0; ks < 4; ks++) {
                    short8 bfr = *(const short8*)(wb + ks * 32);
                    acc = __builtin_amdgcn_mfma_f32_16x16x32_bf16(a[ks], bfr, acc, 0, 0, 0);
                }
                int col = n0 + ml;
                float bb = bq[col];
#pragma unroll
                for (int r = 0; r < 4; r++) {
                    int row = quad * 4 + r;
                    if (row < TT) Qs[row * 392 + col] = bfr16(acc[r] + bb);
                }
            }
        }
        __syncthreads();

        // attention scores + softmax: 480 threads, 8 lanes per (h,tq) pair
        if (tid < 480) {
            int pair = tid >> 3, part = tid & 7;
            int h = pair / 15, tq = pair % 15;
            const ushort* qp = Qs + tq * 392 + h * 32 + part * 4;
            float sc[TT];
#pragma unroll
            for (int tk = 0; tk < TT; tk++) {
                const ushort* kp = Qs + tk * 392 + 128 + h * 32 + part * 4;
                uint2 qa = *(const uint2*)(qp);
                uint2 ka = *(const uint2*)(kp);
                float d = ulo(qa.x) * ulo(ka.x) + uhi(qa.x) * uhi(ka.x)
                        + ulo(qa.y) * ulo(ka.y) + uhi(qa.y) * uhi(ka.y);
                d += __shfl_xor(d, 1, 64);
                d += __shfl_xor(d, 2, 64);
                d += __shfl_xor(d, 4, 64);
                sc[tk] = d * 0.17677669529663689f;
            }
            if (part == 0) {
                float mx = -1e30f;
#pragma unroll
                for (int tk = 0; tk < TT; tk++) mx = fmaxf(mx, sc[tk]);
                float sum = 0.f;
#pragma unroll
                for (int tk = 0; tk < TT; tk++) { float e = __expf(sc[tk] - mx); sc[tk] = e; sum += e; }
                float r = 1.f / sum;
#pragma unroll
                for (int tk = 0; tk < TT; tk++) Att[pair * 16 + tk] = sc[tk] * r;
            }
        }
        __syncthreads();

        // o = att @ v -> Hs (bf16)
        for (int f = tid; f < TT * 64; f += 512) {
            int t = f >> 6, cp = f & 63;
            int h = cp >> 4;
            const float* ap = Att + (h * 15 + t) * 16;
            const ushort* vp = Qs + 256 + 2 * cp;
            float a0 = 0.f, a1 = 0.f;
#pragma unroll
            for (int tk = 0; tk < TT; tk++) {
                float w = ap[tk];
                unsigned pk = *(const unsigned*)(vp + tk * 392);
                a0 += w * ulo(pk);
                a1 += w * uhi(pk);
            }
            ((unsigned*)(Hs + t * 136))[cp] = fpack2(a0, a1);
        }
        __syncthreads();

        // proj + residual: N=128 -> 8 tiles, 1 per wave
        {
            short8 a[4];
            const ushort* ar = Hs + ml * 136 + quad * 8;
#pragma unroll
            for (int ks = 0; ks < 4; ks++) a[ks] = *(const short8*)(ar + ks * 32);
            int n0 = wv * 16;
            f32x4 acc = (f32x4){0.f, 0.f, 0.f, 0.f};
            const ushort* wb = WoB + (size_t)(l * 128 + n0 + ml) * 128 + quad * 8;
#pragma unroll
            for (int ks = 0; ks < 4; ks++) {
                short8 bfr = *(const short8*)(wb + ks * 32);
                acc = __builtin_amdgcn_mfma_f32_16x16x32_bf16(a[ks], bfr, acc, 0, 0, 0);
            }
            int col = n0 + ml;
            float bb = bol[col];
#pragma unroll
            for (int r = 0; r < 4; r++) {
                int row = quad * 4 + r;
                if (row < TT) As[row * 132 + col] += acc[r] + bb;
            }
        }
        __syncthreads();

        // LN2 fused
        for (int r = wv; r < TT; r += 8) {
            float2 v = *(const float2*)(As + r * 132 + lane * 2);
            float s = v.x + v.y, q = v.x * v.x + v.y * v.y;
            for (int off = 32; off; off >>= 1) {
                s += __shfl_xor(s, off, 64);
                q += __shfl_xor(q, off, 64);
            }
            float mu = s * (1.f / 128.f);
            float rs = rsqrtf(q * (1.f / 128.f) - mu * mu + EPSv);
            float x0 = (v.x - mu) * rs * g2[2 * lane]     + be2[2 * lane];
            float x1 = (v.y - mu) * rs * g2[2 * lane + 1] + be2[2 * lane + 1];
            ((unsigned*)(Ab + r * 136))[lane] = fpack2(x0, x1);
        }
        __syncthreads();

        // ff1 (K=128, N=512 -> 32 tiles, 4 per wave)
        {
            short8 a[4];
            const ushort* ar = Ab + ml * 136 + quad * 8;
#pragma unroll
            for (int ks = 0; ks < 4; ks++) a[ks] = *(const short8*)(ar + ks * 32);
#pragma unroll
            for (int i = 0; i < 4; i++) {
                int n0 = (wv * 4 + i) * 16;
                f32x4 acc = (f32x4){0.f, 0.f, 0.f, 0.f};
                const ushort* wb = W1B + (size_t)(l * 512 + n0 + ml) * 128 + quad * 8;
#pragma unroll
                for (int ks = 0; ks < 4; ks++) {
                    short8 bfr = *(const short8*)(wb + ks * 32);
                    acc = __builtin_amdgcn_mfma_f32_16x16x32_bf16(a[ks], bfr, acc, 0, 0, 0);
                }
                int col = n0 + ml;
                float bb = b1l[col];
#pragma unroll
                for (int r = 0; r < 4; r++) {
                    int row = quad * 4 + r;
                    if (row < TT) Fs[row * 520 + col] = bfr16(fmaxf(acc[r] + bb, 0.f));
                }
            }
        }
        __syncthreads();

        // ff2 + residual (K=512, N=128 -> 8 tiles, 1 per wave)
        {
            f32x4 acc = (f32x4){0.f, 0.f, 0.f, 0.f};
            const ushort* ar = Fs + ml * 520 + quad * 8;
            int n0 = wv * 16;
            const ushort* wb = W2B + (size_t)(l * 128 + n0 + ml) * 512 + quad * 8;
            for (int ks = 0; ks < 16; ks++) {
                short8 a   = *(const short8*)(ar + ks * 32);
                short8 bfr = *(const short8*)(wb + ks * 32);
                acc = __builtin_amdgcn_mfma_f32_16x16x32_bf16(a, bfr, acc, 0, 0, 0);
            }
            int col = n0 + ml;
            float bb = b2l[col];
#pragma unroll
            for (int r = 0; r < 4; r++) {
                int row = quad * 4 + r;
                if (row < TT) As[row * 132 + col] += acc[r] + bb;
            }
        }
        __syncthreads();
    }

    if (tid < 128) {
        float s = 0.f;
#pragma unroll
        for (int t = 0; t < TT; t++) s += As[t * 132 + tid];
        out[(size_t)b * 26 * Cc + 24 * Cc + tid] = s * (1.f / 15.f);
    } else if (tid < 256) {
        int co = tid - 128;
        float v = ss[b] * Wsc[co] + bsc[co];
        out[(size_t)b * 26 * Cc + 25 * Cc + co] = fmaxf(v, 0.f);
    }
}

// ---------------------------------------------------------------------------
extern "C" void kernel_launch(void* const* d_in, const int* in_sizes, int n_in,
                              void* d_out, int out_size, void* d_ws, size_t ws_size,
                              hipStream_t stream)
{
    (void)in_sizes; (void)n_in; (void)out_size; (void)ws_size;
    const int*   xx   = (const int*)d_in[0];
    const float* ss   = (const float*)d_in[1];
    const float* Win  = (const float*)d_in[2];
    const float* b_in = (const float*)d_in[3];
    const float* Wl   = (const float*)d_in[4];
    const float* bl   = (const float*)d_in[5];
    const float* Wr   = (const float*)d_in[6];
    const float* lng  = (const float*)d_in[7];
    const float* lnb  = (const float*)d_in[8];
    const float* Wqkv = (const float*)d_in[9];
    const float* bqkv = (const float*)d_in[10];
    const float* Wo   = (const float*)d_in[11];
    const float* bo   = (const float*)d_in[12];
    const float* ln1g = (const float*)d_in[13];
    const float* ln1b = (const float*)d_in[14];
    const float* ln2g = (const float*)d_in[15];
    const float* ln2b = (const float*)d_in[16];
    const float* W1   = (const float*)d_in[17];
    const float* b1   = (const float*)d_in[18];
    const float* W2   = (const float*)d_in[19];
    const float* b2   = (const float*)d_in[20];
    const float* Wact = (const float*)d_in[21];
    const float* bact = (const float*)d_in[22];
    const float* Wsc  = (const float*)d_in[23];
    const float* bsc  = (const float*)d_in[24];
    float* out = (float*)d_out;

    char* ws = (char*)d_ws;
    size_t off = 0;
    float* WlT  = (float*)(ws + off); off += 384 * 128 * 4;
    ushort* WB    = (ushort*)(ws + off); off += (size_t)3 * 2 * 128 * 128 * 2;
    ushort* WactB = (ushort*)(ws + off); off += 128 * 512 * 2;
    ushort* WqkvB = (ushort*)(ws + off); off += 768 * 128 * 2;
    ushort* WoB   = (ushort*)(ws + off); off += 256 * 128 * 2;
    ushort* W1B   = (ushort*)(ws + off); off += 1024 * 128 * 2;
    ushort* W2B   = (ushort*)(ws + off); off += 256 * 512 * 2;

    k_prep<<<502, 256, 0, stream>>>(Wl, Wr, WlT,
                                    Wact, Wqkv, Wo, W1, W2, WactB,
                                    WB);

    k_torso<<<Bsz, 1024, 0, stream>>>(xx, ss, Win, b_in, WB,
                                      (const float4*)WlT, bl, lng, lnb, out);

    k_tf3<<<Bsz, 512, 0, stream>>>(xx, ss,
                                   WactB, bact, WqkvB, bqkv, WoB, bo,
                                   ln1g, ln1b, ln2g, ln2b,
                                   W1B, b1, W2B, b2,
                                   Wsc, bsc, out);
}